// Round 2
// baseline (15130.901 us; speedup 1.0000x reference)
//
#include <hip/hip_runtime.h>
#include <hip/hip_bf16.h>

#define BB 16
#define NN 2048
#define KNN 20
#define CH 512

typedef __hip_bfloat16 bf16;

__device__ __forceinline__ float b2f(bf16 v){ return __bfloat162float(v); }

// order-preserving float->uint map for atomicMax on floats (incl. negatives)
__device__ __forceinline__ unsigned f2key(float f){
  unsigned u = __float_as_uint(f);
  return (u & 0x80000000u) ? ~u : (u | 0x80000000u);
}
__device__ __forceinline__ float key2f(unsigned k){
  unsigned u = (k & 0x80000000u) ? (k & 0x7FFFFFFFu) : ~k;
  return __uint_as_float(u);
}

// ---------------- dtype detector: is the input bf16 (1) or fp32 (0)? ----------------
// If data is fp32 but read as bf16, even-indexed bf16 elements are the LOW 16 bits of
// floats -> near-uniform exponent -> rarely in [1e-6,1e6]. True bf16 N(0,1) ~always is.
__global__ void k_detect(const unsigned short* __restrict__ xr, int* __restrict__ flag){
  __shared__ int cnt;
  if (threadIdx.x == 0) cnt = 0;
  __syncthreads();
  unsigned short u = xr[threadIdx.x * 2];
  float v = __uint_as_float(((unsigned)u) << 16);
  float a = fabsf(v);
  int ok = (a > 1e-6f && a < 1e6f) ? 1 : 0;   // NaN/Inf -> 0
  atomicAdd(&cnt, ok);
  __syncthreads();
  if (threadIdx.x == 0) flag[0] = (cnt >= 160) ? 1 : 0;
}

// convert one tensor (bf16 or fp32 per flag) to fp32
__global__ void k_convert(const void* __restrict__ src, float* __restrict__ dst, int n,
                          const int* __restrict__ flag){
  int i = blockIdx.x*256 + threadIdx.x;
  if (i >= n) return;
  dst[i] = flag[0] ? b2f(((const bf16*)src)[i]) : ((const float*)src)[i];
}

// ---------------- transpose x [B,3,N] -> XT [B,N,3] fp32 ----------------
__global__ void k_transpose(const void* __restrict__ x, const int* __restrict__ flag,
                            float* __restrict__ xt){
  int i = blockIdx.x*256 + threadIdx.x;      // [0, B*N)
  if (i >= BB*NN) return;
  int b = i / NN, n = i - b*NN;
  int isbf = flag[0];
  #pragma unroll
  for (int c = 0; c < 3; ++c){
    size_t off = ((size_t)b*3 + c)*NN + n;
    float v = isbf ? b2f(((const bf16*)x)[off]) : ((const float*)x)[off];
    xt[(size_t)i*3 + c] = v;
  }
}

__global__ void k_init(unsigned* __restrict__ hmaxk, float* __restrict__ hsum){
  int i = blockIdx.x*256 + threadIdx.x;
  if (i < BB*1024){ hmaxk[i] = 0u; hsum[i] = 0.f; }
}

// ---------------- segmented KNN: per-query top-20 over one 512-candidate segment
// grid (N/64, CB, 4), block 64 (one wave). X rows: rowStride floats, C used.
template<int C, int TC>
__global__ __launch_bounds__(64) void k_knn_seg(const float* __restrict__ X, int rowStride,
                                                float* __restrict__ segv, int* __restrict__ segi){
  __shared__ float cf[TC*C];
  __shared__ float csq[TC];
  __shared__ float tv[KNN*64];
  __shared__ int   ti[KNN*64];
  const int tid = threadIdx.x;
  const int b = blockIdx.y;                 // chunk-local batch
  const int q = blockIdx.x*64 + tid;
  const int s = blockIdx.z;
  const int segLen = NN/4;
  const int j0 = s*segLen;
  const float* Xb = X + (size_t)b*NN*rowStride;

  float qf[C];
  #pragma unroll
  for (int c = 0; c < C; ++c) qf[c] = Xb[(size_t)q*rowStride + c];
  float sqq = 0.f;
  #pragma unroll
  for (int c = 0; c < C; ++c) sqq += qf[c]*qf[c];

  #pragma unroll
  for (int t = 0; t < KNN; ++t){ tv[t*64+tid] = -INFINITY; ti[t*64+tid] = 0; }
  float minv = -INFINITY;

  for (int t0 = 0; t0 < segLen; t0 += TC){
    __syncthreads();
    for (int xx = tid; xx < TC*C; xx += 64){
      int cand = xx / C, c = xx - cand*C;
      cf[xx] = Xb[(size_t)(j0 + t0 + cand)*rowStride + c];
    }
    __syncthreads();
    for (int cand = tid; cand < TC; cand += 64){
      float sq = 0.f;
      for (int cc = 0; cc < C; ++cc){
        int c = (cc + tid) % C;
        float v = cf[cand*C + c]; sq += v*v;
      }
      csq[cand] = sq;
    }
    __syncthreads();
    for (int j = 0; j < TC; ++j){
      float dot = 0.f;
      #pragma unroll
      for (int c = 0; c < C; ++c) dot += qf[c]*cf[j*C+c];   // LDS broadcast
      float d = 2.f*dot - sqq - csq[j];
      if (d > minv){                     // strict >: later ties excluded (top_k stable)
        int t = KNN-1;
        while (t > 0){
          float pv = tv[(t-1)*64+tid];
          if (pv >= d) break;            // equal values keep earlier index first
          tv[t*64+tid] = pv; ti[t*64+tid] = ti[(t-1)*64+tid];
          --t;
        }
        tv[t*64+tid] = d; ti[t*64+tid] = j0 + t0 + j;
        minv = tv[(KNN-1)*64+tid];
      }
    }
  }
  size_t base = ((size_t)(b*NN + q)*4 + s)*KNN;
  #pragma unroll
  for (int t = 0; t < KNN; ++t){ segv[base+t] = tv[t*64+tid]; segi[base+t] = ti[t*64+tid]; }
}

// merge 4 sorted 20-lists per query -> final top-20 (ties -> lower segment = lower index)
__global__ void k_knn_merge(const float* __restrict__ segv, const int* __restrict__ segi,
                            int* __restrict__ idx){
  int q = blockIdx.x*64 + threadIdx.x;       // [0, CB*N)
  const float* v  = segv + (size_t)q*4*KNN;
  const int*   ii = segi + (size_t)q*4*KNN;
  int p0=0,p1=0,p2=0,p3=0;
  for (int t = 0; t < KNN; ++t){
    float v0 = v[0*KNN+p0], v1 = v[1*KNN+p1], v2 = v[2*KNN+p2], v3 = v[3*KNN+p3];
    int bs = 0; float bv = v0;
    if (v1 > bv){ bv = v1; bs = 1; }
    if (v2 > bv){ bv = v2; bs = 2; }
    if (v3 > bv){ bv = v3; bs = 3; }
    int bi;
    if      (bs == 0){ bi = ii[p0];         p0++; }
    else if (bs == 1){ bi = ii[KNN+p1];     p1++; }
    else if (bs == 2){ bi = ii[2*KNN+p2];   p2++; }
    else             { bi = ii[3*KNN+p3];   p3++; }
    idx[(size_t)q*KNN + t] = bi;            // within-batch index [0,N)
  }
}

// ---------------- P/Q matmul: PQ[i][oo] = dot(X[i], W[r, cb:cb+Cin]) ----------------
template<int TP>
__global__ __launch_bounds__(256) void k_pq(const float* __restrict__ X, int rowStride,
                     int Cin, int O, const float* __restrict__ W, float* __restrict__ PQ){
  extern __shared__ float xs[];            // TP*Cin
  int p0 = blockIdx.x*TP;
  int tid = threadIdx.x;
  for (int xx = tid; xx < TP*Cin; xx += 256){
    int p = xx / Cin, c = xx - p*Cin;
    xs[xx] = X[(size_t)(p0+p)*rowStride + c];
  }
  __syncthreads();
  int OO = 2*O;
  for (int oo = tid; oo < OO; oo += 256){
    int r  = (oo < O) ? oo : oo - O;
    int cb = (oo < O) ? 0 : Cin;
    const float* wrow = W + (size_t)r*2*Cin + cb;
    float acc[TP];
    #pragma unroll
    for (int p = 0; p < TP; ++p) acc[p] = 0.f;
    for (int c = 0; c < Cin; ++c){
      float w = wrow[c];
      #pragma unroll
      for (int p = 0; p < TP; ++p) acc[p] += w * xs[p*Cin+c];
    }
    #pragma unroll
    for (int p = 0; p < TP; ++p) PQ[(size_t)(p0+p)*OO + oo] = acc[p];
  }
}

// ---------------- gather-max + BN + LeakyReLU (act commutes with max: scale>0) ------
__global__ void k_gathermax(const float* __restrict__ PQ, const int* __restrict__ idx,
                            const float* __restrict__ bn, int O,
                            float* __restrict__ CAT, int coff){
  __shared__ int nb[KNN];
  int i = blockIdx.x;                      // chunk-local point
  int o = threadIdx.x;                     // [0, O)
  int b = i / NN;
  if (o < KNN) nb[o] = idx[(size_t)i*KNN + o];
  __syncthreads();
  int OO = 2*O;
  const float* pqi = PQ + (size_t)i*OO;
  float pi = pqi[o], qi = pqi[O+o];
  float m = -INFINITY;
  #pragma unroll
  for (int t = 0; t < KNN; ++t){
    float v = PQ[((size_t)b*NN + nb[t])*OO + o];
    m = fmaxf(m, v);
  }
  float h = m - pi + qi;
  float g = bn[o], be = bn[O+o], mu = bn[2*O+o], va = bn[3*O+o];
  float sc = g / sqrtf(va + 1e-5f);
  h = (h - mu)*sc + be;
  h = (h >= 0.f) ? h : 0.2f*h;
  CAT[(size_t)i*CH + coff + o] = h;
}

// ---------------- h = act(bn5(cat @ W5^T)) fused with global max/sum pooling --------
__global__ __launch_bounds__(256) void k_w5(const float* __restrict__ CAT,
                   const float* __restrict__ W5, const float* __restrict__ bn5,
                   unsigned* __restrict__ hmaxk, float* __restrict__ hsum, int b0){
  __shared__ float xs[16*512];             // 32 KB
  int p0 = blockIdx.x*16;                  // chunk-local
  int bg = b0 + p0 / NN;                   // global batch
  int tid = threadIdx.x;
  for (int xx = tid; xx < 16*512; xx += 256) xs[xx] = CAT[(size_t)p0*512 + xx];
  __syncthreads();
  float acc[4][16];
  #pragma unroll
  for (int j = 0; j < 4; ++j)
    #pragma unroll
    for (int p = 0; p < 16; ++p) acc[j][p] = 0.f;
  const float* w0 = W5 + (size_t)(tid      )*512;
  const float* w1 = W5 + (size_t)(tid + 256)*512;
  const float* w2 = W5 + (size_t)(tid + 512)*512;
  const float* w3 = W5 + (size_t)(tid + 768)*512;
  for (int c = 0; c < 512; c += 4){
    float4 xv[16];
    #pragma unroll
    for (int p = 0; p < 16; ++p) xv[p] = *(const float4*)&xs[p*512 + c];
    float4 wv[4];
    wv[0] = *(const float4*)&w0[c]; wv[1] = *(const float4*)&w1[c];
    wv[2] = *(const float4*)&w2[c]; wv[3] = *(const float4*)&w3[c];
    #pragma unroll
    for (int j = 0; j < 4; ++j){
      #pragma unroll
      for (int p = 0; p < 16; ++p)
        acc[j][p] += wv[j].x*xv[p].x + wv[j].y*xv[p].y + wv[j].z*xv[p].z + wv[j].w*xv[p].w;
    }
  }
  #pragma unroll
  for (int j = 0; j < 4; ++j){
    int oo = tid + j*256;
    float g = bn5[oo], be = bn5[1024+oo], mu = bn5[2048+oo], va = bn5[3072+oo];
    float sc = g / sqrtf(va + 1e-5f);
    float lmax = -INFINITY, lsum = 0.f;
    #pragma unroll
    for (int p = 0; p < 16; ++p){
      float h = (acc[j][p] - mu)*sc + be;
      h = (h >= 0.f) ? h : 0.2f*h;
      lmax = fmaxf(lmax, h); lsum += h;
    }
    atomicMax(&hmaxk[bg*1024 + oo], f2key(lmax));
    atomicAdd(&hsum[bg*1024 + oo], lsum);
  }
}

// ---------------- head: [max|mean] -> FC512 -> FC256 -> FC40, one block per batch ----
__global__ __launch_bounds__(512) void k_head(const unsigned* __restrict__ hmaxk, const float* __restrict__ hsum,
                    const float* __restrict__ Wl1, const float* __restrict__ bn6,
                    const float* __restrict__ Wl2, const float* __restrict__ bl2, const float* __restrict__ bn7,
                    const float* __restrict__ Wl3, const float* __restrict__ bl3,
                    void* __restrict__ out, const int* __restrict__ flag){
  __shared__ float hc[2048];
  __shared__ float h2s[512];
  __shared__ float h3s[256];
  int b = blockIdx.x, tid = threadIdx.x;
  for (int xv = tid; xv < 1024; xv += 512){
    hc[xv]        = key2f(hmaxk[b*1024 + xv]);
    hc[1024 + xv] = hsum[b*1024 + xv] * (1.0f/2048.0f);
  }
  __syncthreads();
  {
    const float* w = Wl1 + (size_t)tid*2048;
    float acc = 0.f;
    for (int c = 0; c < 2048; ++c) acc += w[c] * hc[c];
    float g = bn6[tid], be = bn6[512+tid], mu = bn6[1024+tid], va = bn6[1536+tid];
    float sc = g / sqrtf(va + 1e-5f);
    float h = (acc - mu)*sc + be;
    h2s[tid] = (h >= 0.f) ? h : 0.2f*h;
  }
  __syncthreads();
  if (tid < 256){
    const float* w = Wl2 + (size_t)tid*512;
    float acc = 0.f;
    for (int c = 0; c < 512; ++c) acc += w[c] * h2s[c];
    acc += bl2[tid];
    float g = bn7[tid], be = bn7[256+tid], mu = bn7[512+tid], va = bn7[768+tid];
    float sc = g / sqrtf(va + 1e-5f);
    float h = (acc - mu)*sc + be;
    h3s[tid] = (h >= 0.f) ? h : 0.2f*h;
  }
  __syncthreads();
  if (tid < 40){
    const float* w = Wl3 + (size_t)tid*256;
    float acc = 0.f;
    for (int c = 0; c < 256; ++c) acc += w[c] * h3s[c];
    acc += bl3[tid];
    if (flag[0]) ((bf16*)out)[b*40 + tid] = __float2bfloat16(acc);
    else         ((float*)out)[b*40 + tid] = acc;
  }
}

extern "C" void kernel_launch(void* const* d_in, const int* in_sizes, int n_in,
                              void* d_out, int out_size, void* d_ws, size_t ws_size,
                              hipStream_t stream){
  const size_t P = (size_t)BB*NN;          // 32768 points
  float* ws = (float*)d_ws;

  // ---- fixed region ----
  int*   FLAG = (int*)ws;                  // 16 slots
  float* WBUF = ws + 16;                   // fp32 weights, 1,814,184 floats
  // weight offsets (cumulative, element counts from reference shapes)
  const int nW1=384, nbn1=256, nW2=8192, nbn2=256, nW3=16384, nbn3=512,
            nW4=65536, nbn4=1024, nW5=524288, nbn5=4096, nWl1=1048576,
            nbn6=2048, nWl2=131072, nbl2=256, nbn7=1024, nWl3=10240, nbl3=40;
  float* W1f  = WBUF;           float* bn1f = W1f  + nW1;
  float* W2f  = bn1f + nbn1;    float* bn2f = W2f  + nW2;
  float* W3f  = bn2f + nbn2;    float* bn3f = W3f  + nW3;
  float* W4f  = bn3f + nbn3;    float* bn4f = W4f  + nW4;
  float* W5f  = bn4f + nbn4;    float* bn5f = W5f  + nW5;
  float* Wl1f = bn5f + nbn5;    float* bn6f = Wl1f + nWl1;
  float* Wl2f = bn6f + nbn6;    float* bl2f = Wl2f + nWl2;
  float* bn7f = bl2f + nbl2;    float* Wl3f = bn7f + nbn7;
  float* bl3f = Wl3f + nWl3;
  const size_t WTOT = (size_t)(bl3f - WBUF) + nbl3;      // 1,814,184
  float*    XT    = WBUF + WTOT;                          // P*3
  unsigned* HMAXK = (unsigned*)(XT + P*3);                // B*1024
  float*    HSUM  = (float*)(HMAXK + BB*1024);            // B*1024
  float*    CHUNK = HSUM + BB*1024;

  // ---- chunked region: pick largest CB (batches per pass) that fits ws ----
  const size_t fixedF = 16 + WTOT + P*3 + 2*(size_t)BB*1024;
  int CB = 16;
  while (CB > 1 && (fixedF + (size_t)CB*NN*1044)*sizeof(float) > ws_size) CB >>= 1;
  const size_t CBN = (size_t)CB*NN;
  int*   IDX  = (int*)CHUNK;               // CBN*20
  float* CAT  = CHUNK + CBN*KNN;           // CBN*512
  float* PQ   = CAT + CBN*512;             // CBN*512 (SEGV/SEGI overlaid)
  float* SEGV = PQ;                        // CBN*4*20
  int*   SEGI = (int*)(PQ + CBN*4*KNN);    // CBN*4*20

  // ---- dtype detect + weight conversion ----
  k_detect<<<1, 256, 0, stream>>>((const unsigned short*)d_in[0], FLAG);
  const int widx[17]  = {1,2,3,4,5,6,7,8,9,10,11,12,13,14,15,16,17};
  float*    wdst[17]  = {W1f,bn1f,W2f,bn2f,W3f,bn3f,W4f,bn4f,W5f,bn5f,Wl1f,bn6f,Wl2f,bl2f,bn7f,Wl3f,bl3f};
  const int wcnt[17]  = {nW1,nbn1,nW2,nbn2,nW3,nbn3,nW4,nbn4,nW5,nbn5,nWl1,nbn6,nWl2,nbl2,nbn7,nWl3,nbl3};
  for (int i = 0; i < 17; ++i)
    k_convert<<<(wcnt[i]+255)/256, 256, 0, stream>>>(d_in[widx[i]], wdst[i], wcnt[i], FLAG);
  k_transpose<<<(int)(P/256), 256, 0, stream>>>(d_in[0], FLAG, XT);
  k_init<<<(BB*1024 + 255)/256, 256, 0, stream>>>(HMAXK, HSUM);

  for (int b0 = 0; b0 < BB; b0 += CB){
    const float* XTc = XT + (size_t)b0*NN*3;
    dim3 kg(NN/64, CB, 4);

    // EC1: XT (C=3) -> CAT[:, 0:64]
    k_knn_seg<3,128><<<kg, 64, 0, stream>>>(XTc, 3, SEGV, SEGI);
    k_knn_merge<<<(int)(CBN/64), 64, 0, stream>>>(SEGV, SEGI, IDX);
    k_pq<16><<<(int)(CBN/16), 256, 16*3*sizeof(float), stream>>>(XTc, 3, 3, 64, W1f, PQ);
    k_gathermax<<<(int)CBN, 64, 0, stream>>>(PQ, IDX, bn1f, 64, CAT, 0);

    // EC2: x1 = CAT[:, 0:64] -> CAT[:, 64:128]
    k_knn_seg<64,128><<<kg, 64, 0, stream>>>(CAT + 0, 512, SEGV, SEGI);
    k_knn_merge<<<(int)(CBN/64), 64, 0, stream>>>(SEGV, SEGI, IDX);
    k_pq<16><<<(int)(CBN/16), 256, 16*64*sizeof(float), stream>>>(CAT + 0, 512, 64, 64, W2f, PQ);
    k_gathermax<<<(int)CBN, 64, 0, stream>>>(PQ, IDX, bn2f, 64, CAT, 64);

    // EC3: x2 = CAT[:, 64:128] -> CAT[:, 128:256]
    k_knn_seg<64,128><<<kg, 64, 0, stream>>>(CAT + 64, 512, SEGV, SEGI);
    k_knn_merge<<<(int)(CBN/64), 64, 0, stream>>>(SEGV, SEGI, IDX);
    k_pq<16><<<(int)(CBN/16), 256, 16*64*sizeof(float), stream>>>(CAT + 64, 512, 64, 128, W3f, PQ);
    k_gathermax<<<(int)CBN, 128, 0, stream>>>(PQ, IDX, bn3f, 128, CAT, 128);

    // EC4: x3 = CAT[:, 128:256] -> CAT[:, 256:512]
    k_knn_seg<128,64><<<kg, 64, 0, stream>>>(CAT + 128, 512, SEGV, SEGI);
    k_knn_merge<<<(int)(CBN/64), 64, 0, stream>>>(SEGV, SEGI, IDX);
    k_pq<16><<<(int)(CBN/16), 256, 16*128*sizeof(float), stream>>>(CAT + 128, 512, 128, 256, W4f, PQ);
    k_gathermax<<<(int)CBN, 256, 0, stream>>>(PQ, IDX, bn4f, 256, CAT, 256);

    // W5 + BN + act + fused global max/mean pooling
    k_w5<<<(int)(CBN/16), 256, 0, stream>>>(CAT, W5f, bn5f, HMAXK, HSUM, b0);
  }

  // head FCs
  k_head<<<BB, 512, 0, stream>>>(HMAXK, HSUM, Wl1f, bn6f, Wl2f, bl2f, bn7f, Wl3f, bl3f,
                                 d_out, FLAG);
}

// Round 5
// 10998.637 us; speedup vs baseline: 1.3757x; 1.3757x over previous
//
#include <hip/hip_runtime.h>
#include <hip/hip_bf16.h>

#define BB 16
#define NN 2048
#define PP (BB*NN)
#define KNN 20

typedef __hip_bfloat16 bf16;
typedef unsigned short u16;
typedef unsigned int u32;

__device__ __forceinline__ float bu2f(u16 u){ return __uint_as_float(((u32)u) << 16); }
__device__ __forceinline__ float lo16(u32 u){ return __uint_as_float(u << 16); }
__device__ __forceinline__ float hi16(u32 u){ return __uint_as_float(u & 0xffff0000u); }
__device__ __forceinline__ u16 f2bu(float f){ bf16 h = __float2bfloat16(f); return *(u16*)&h; }
__device__ __forceinline__ float lrelu(float h){ return (h >= 0.f) ? h : 0.2f*h; }

// order-preserving float->uint map for atomicMax on floats
__device__ __forceinline__ u32 f2key(float f){
  u32 u = __float_as_uint(f);
  return (u & 0x80000000u) ? ~u : (u | 0x80000000u);
}
__device__ __forceinline__ float key2f(u32 k){
  u32 u = (k & 0x80000000u) ? (k & 0x7FFFFFFFu) : ~k;
  return __uint_as_float(u);
}

// dtype-generic weight accessors (BF: raw bf16 u16; else fp32)
template<bool BF> __device__ __forceinline__ float wget(const void* p, size_t i){
  return BF ? bu2f(((const u16*)p)[i]) : ((const float*)p)[i];
}
template<bool BF> __device__ __forceinline__ void wload8(const void* p, size_t base, float w[8]){
  if (BF){
    const uint4 u = *(const uint4*)((const u16*)p + base);
    w[0]=lo16(u.x); w[1]=hi16(u.x); w[2]=lo16(u.y); w[3]=hi16(u.y);
    w[4]=lo16(u.z); w[5]=hi16(u.z); w[6]=lo16(u.w); w[7]=hi16(u.w);
  } else {
    const float4* f = (const float4*)((const float*)p + base);
    float4 a = f[0], b = f[1];
    w[0]=a.x; w[1]=a.y; w[2]=a.z; w[3]=a.w; w[4]=b.x; w[5]=b.y; w[6]=b.z; w[7]=b.w;
  }
}

// ---------------- dtype detector: bf16 (1) vs fp32 (0) ------------------------------
// fp32 read as u16: even elements are float low-halves -> near-uniform exponent ->
// rarely in [1e-6,1e6]. bf16 N(0,1): ~always in range.
__global__ void k_detect(const u16* __restrict__ xr, int* __restrict__ flag){
  __shared__ int cnt;
  if (threadIdx.x == 0) cnt = 0;
  __syncthreads();
  float v = bu2f(xr[threadIdx.x * 2]);
  float a = fabsf(v);
  int ok = (a > 1e-6f && a < 1e6f) ? 1 : 0;   // NaN/Inf -> 0
  atomicAdd(&cnt, ok);
  __syncthreads();
  if (threadIdx.x == 0) flag[0] = (cnt >= 160) ? 1 : 0;
}

// ---------------- prep: transpose x [B,3,N] -> XT [P,3] fp32, SQ, pool init ---------
template<bool BF>
__global__ void k_prep(const int* __restrict__ FLAG, const void* __restrict__ x,
                       float* __restrict__ XT, float* __restrict__ SQ,
                       u32* __restrict__ hmaxk, float* __restrict__ hsum){
  if (FLAG[0] != (BF ? 1 : 0)) return;
  int i = blockIdx.x*256 + threadIdx.x;
  if (i >= PP) return;
  int b = i / NN, n = i - b*NN;
  float s = 0.f;
  #pragma unroll
  for (int c = 0; c < 3; ++c){
    float v = wget<BF>(x, ((size_t)b*3 + c)*NN + n);
    XT[(size_t)i*3 + c] = v;
    s += v*v;                          // ascending c — must match k_knn dot order
  }
  SQ[i] = s;
  if (i < BB*1024){ hmaxk[i] = 0u; hsum[i] = 0.f; }
}

// ---------------- SQ[i] = sum_c x[i,c]^2 (ascending, internal bf16 features) --------
template<int Cin>
__global__ void k_sq(const u16* __restrict__ xin, float* __restrict__ SQ){
  int i = blockIdx.x*256 + threadIdx.x;
  if (i >= PP) return;
  const u32* r = (const u32*)(xin + (size_t)i*Cin);
  float s = 0.f;
  for (int c = 0; c < Cin/2; ++c){
    u32 u = r[c];
    float a = lo16(u), b = hi16(u);    // lo then hi = ascending channel order
    s += a*a; s += b*b;
  }
  SQ[i] = s;
}

// ---------------- KNN: block = 64 queries x 4 waves (each wave = one 512-cand seg) --
// BF here refers to the INTERNAL feature storage (XT fp32 vs x bf16), not input dtype.
template<int C, int TC, bool BF>
__global__ __launch_bounds__(256) void k_knn(const void* __restrict__ xin,
                                             const float* __restrict__ SQ,
                                             u16* __restrict__ IDX){
  __shared__ float cf[4][TC*C];
  __shared__ float csqv[4][TC];
  __shared__ float tv[4][KNN][64];
  __shared__ u16   ti[4][KNN][64];
  const int tid = threadIdx.x, w = tid >> 6, lane = tid & 63;
  const int b = blockIdx.y;
  const int q = blockIdx.x*64 + lane;
  const int j0 = w * 512;              // this wave's candidate segment

  float qf[C];
  if (BF){
    const u16* xq = (const u16*)xin + ((size_t)b*NN + q)*C;
    #pragma unroll
    for (int c = 0; c < C; ++c) qf[c] = bu2f(xq[c]);
  } else {
    const float* xq = (const float*)xin + ((size_t)b*NN + q)*C;
    #pragma unroll
    for (int c = 0; c < C; ++c) qf[c] = xq[c];
  }
  const float sqq = SQ[b*NN + q];

  #pragma unroll
  for (int t = 0; t < KNN; ++t){ tv[w][t][lane] = -INFINITY; ti[w][t][lane] = 0; }
  float minv = -INFINITY;

  for (int t0 = 0; t0 < 512; t0 += TC){
    __syncthreads();
    if (BF){
      const u32* src = (const u32*)((const u16*)xin + ((size_t)b*NN + j0 + t0)*C);
      for (int k = lane; k < TC*C/2; k += 64){
        u32 u = src[k];
        cf[w][2*k] = lo16(u); cf[w][2*k+1] = hi16(u);
      }
    } else {
      const float* src = (const float*)xin + ((size_t)b*NN + j0 + t0)*C;
      for (int k = lane; k < TC*C; k += 64) cf[w][k] = src[k];
    }
    for (int k = lane; k < TC; k += 64) csqv[w][k] = SQ[b*NN + j0 + t0 + k];
    __syncthreads();
    for (int j = 0; j < TC; ++j){
      float dot = 0.f;
      #pragma unroll
      for (int c = 0; c < C; ++c) dot += qf[c]*cf[w][j*C + c];  // LDS broadcast
      float d = 2.f*dot - sqq - csqv[w][j];
      if (d > minv){                   // strict >: later ties excluded (top_k stable)
        int t = KNN-1;
        while (t > 0){
          float pv = tv[w][t-1][lane];
          if (pv >= d) break;          // equal keeps earlier index first
          tv[w][t][lane] = pv; ti[w][t][lane] = ti[w][t-1][lane];
          --t;
        }
        tv[w][t][lane] = d; ti[w][t][lane] = (u16)(j0 + t0 + j);
        minv = tv[w][KNN-1][lane];
      }
    }
  }
  __syncthreads();
  if (tid < 64){                       // wave 0 merges the 4 sorted lists per query
    int p0=0,p1=0,p2=0,p3=0;
    u16* op = IDX + ((size_t)b*NN + q)*KNN;
    for (int t = 0; t < KNN; ++t){
      float v0 = tv[0][p0][tid], v1 = tv[1][p1][tid], v2 = tv[2][p2][tid], v3 = tv[3][p3][tid];
      int bs = 0; float bv = v0;
      if (v1 > bv){ bv = v1; bs = 1; } // strict >: lower segment (lower idx) wins ties
      if (v2 > bv){ bv = v2; bs = 2; }
      if (v3 > bv){ bv = v3; bs = 3; }
      u16 bi;
      if      (bs == 0){ bi = ti[0][p0][tid]; p0++; }
      else if (bs == 1){ bi = ti[1][p1][tid]; p1++; }
      else if (bs == 2){ bi = ti[2][p2][tid]; p2++; }
      else             { bi = ti[3][p3][tid]; p3++; }
      op[t] = bi;
    }
  }
}

// ---------------- EC1 direct (C=3 -> O=64): block = 4 points x 64 channels ----------
template<bool BF>
__global__ __launch_bounds__(256) void k_ec1(const int* __restrict__ FLAG,
                    const float* __restrict__ XT,
                    const u16* __restrict__ IDX1, const void* __restrict__ W1,
                    const void* __restrict__ bn1, u16* __restrict__ x1out){
  if (FLAG[0] != (BF ? 1 : 0)) return;
  __shared__ float nbx[4][21][3];
  __shared__ float W1s[384];
  __shared__ float bn1s[256];
  __shared__ u16   idxL[4][KNN];
  const int tid = threadIdx.x;
  const int g0 = blockIdx.x*4, b = g0 / NN;
  for (int k = tid; k < 384; k += 256) W1s[k] = wget<BF>(W1, k);
  if (tid < 256) bn1s[tid] = wget<BF>(bn1, tid);
  if (tid < 80){ int pt = tid/KNN, t = tid%KNN; idxL[pt][t] = IDX1[(size_t)(g0+pt)*KNN + t]; }
  __syncthreads();
  for (int k = tid; k < 4*21*3; k += 256){
    int row = k/3, c = k - row*3;
    int pt = row/21, slot = row - pt*21;
    int m = (slot < KNN) ? (int)idxL[pt][slot] : (g0 + pt - b*NN);
    nbx[pt][slot][c] = XT[((size_t)b*NN + m)*3 + c];
  }
  __syncthreads();
  int pt = tid >> 6, o = tid & 63;
  float wa0 = W1s[o*6], wa1 = W1s[o*6+1], wa2 = W1s[o*6+2];
  float wb0 = W1s[o*6+3], wb1 = W1s[o*6+4], wb2 = W1s[o*6+5];
  float pmax = -INFINITY;
  #pragma unroll
  for (int t = 0; t < KNN; ++t)
    pmax = fmaxf(pmax, nbx[pt][t][0]*wa0 + nbx[pt][t][1]*wa1 + nbx[pt][t][2]*wa2);
  float po = nbx[pt][20][0]*wa0 + nbx[pt][20][1]*wa1 + nbx[pt][20][2]*wa2;
  float qo = nbx[pt][20][0]*wb0 + nbx[pt][20][1]*wb1 + nbx[pt][20][2]*wb2;
  float h = pmax - po + qo;
  float sc = bn1s[o] / sqrtf(bn1s[192+o] + 1e-5f);
  h = (h - bn1s[128+o])*sc + bn1s[64+o];
  x1out[(size_t)(g0+pt)*64 + o] = f2bu(lrelu(h));
}

// ---------------- EC slab (EC2/EC3): block = (4-out slab, batch); P in LDS ----------
template<int Cin, bool BF>
__global__ __launch_bounds__(256) void k_ec_slab(const int* __restrict__ FLAG,
                    const u16* __restrict__ xin,
                    const u16* __restrict__ idx, const void* __restrict__ W,
                    const void* __restrict__ bn, int O, u16* __restrict__ xout){
  if (FLAG[0] != (BF ? 1 : 0)) return;
  __shared__ float PS[NN][4];          // 32 KB
  __shared__ float Wa[4][Cin], Wb[4][Cin];
  __shared__ float bnp[16];            // [param][j]
  const int b = blockIdx.y, o0 = blockIdx.x*4;
  const int tid = threadIdx.x;
  for (int k = tid; k < 4*2*Cin; k += 256){
    int r = k/(2*Cin), c = k - r*2*Cin;
    float v = wget<BF>(W, (size_t)(o0+r)*2*Cin + c);
    if (c < Cin) Wa[r][c] = v; else Wb[r][c-Cin] = v;
  }
  if (tid < 16){ int pidx = tid/4, j = tid%4; bnp[tid] = wget<BF>(bn, (size_t)pidx*O + o0 + j); }
  __syncthreads();

  float pown[8][4], qreg[8][4];
  #pragma unroll
  for (int rr = 0; rr < 8; ++rr){
    int r = tid + rr*256;
    const u32* xr = (const u32*)(xin + ((size_t)b*NN + r)*Cin);
    float p0=0,p1=0,p2=0,p3=0,q0=0,q1=0,q2=0,q3=0;
    for (int c2 = 0; c2 < Cin/2; ++c2){
      u32 u = xr[c2];
      float xa = lo16(u), xb = hi16(u);
      int c = 2*c2;
      p0 += xa*Wa[0][c]; p1 += xa*Wa[1][c]; p2 += xa*Wa[2][c]; p3 += xa*Wa[3][c];
      q0 += xa*Wb[0][c]; q1 += xa*Wb[1][c]; q2 += xa*Wb[2][c]; q3 += xa*Wb[3][c];
      p0 += xb*Wa[0][c+1]; p1 += xb*Wa[1][c+1]; p2 += xb*Wa[2][c+1]; p3 += xb*Wa[3][c+1];
      q0 += xb*Wb[0][c+1]; q1 += xb*Wb[1][c+1]; q2 += xb*Wb[2][c+1]; q3 += xb*Wb[3][c+1];
    }
    PS[r][0]=p0; PS[r][1]=p1; PS[r][2]=p2; PS[r][3]=p3;
    pown[rr][0]=p0; pown[rr][1]=p1; pown[rr][2]=p2; pown[rr][3]=p3;
    qreg[rr][0]=q0; qreg[rr][1]=q1; qreg[rr][2]=q2; qreg[rr][3]=q3;
  }
  __syncthreads();
  #pragma unroll
  for (int rr = 0; rr < 8; ++rr){
    int r = tid + rr*256;
    const u16* ip = idx + ((size_t)b*NN + r)*KNN;
    float m0=-INFINITY, m1=-INFINITY, m2=-INFINITY, m3=-INFINITY;
    for (int t = 0; t < KNN; ++t){
      int nb = ip[t];
      float4 pv = *(const float4*)&PS[nb][0];
      m0 = fmaxf(m0, pv.x); m1 = fmaxf(m1, pv.y);
      m2 = fmaxf(m2, pv.z); m3 = fmaxf(m3, pv.w);
    }
    float hv[4] = { m0 - pown[rr][0] + qreg[rr][0], m1 - pown[rr][1] + qreg[rr][1],
                    m2 - pown[rr][2] + qreg[rr][2], m3 - pown[rr][3] + qreg[rr][3] };
    u16* op = xout + ((size_t)b*NN + r)*O + o0;
    #pragma unroll
    for (int j = 0; j < 4; ++j){
      float sc = bnp[j] / sqrtf(bnp[12+j] + 1e-5f);
      float h = (hv[j] - bnp[8+j])*sc + bnp[4+j];
      op[j] = f2bu(lrelu(h));
    }
  }
}

// ---------------- fused: x1-recompute + x4-recompute + W5 + BN5 + act + pooling -----
#define PTS 8
template<bool BF>
__global__ __launch_bounds__(256) void k_w5f(const int* __restrict__ FLAG,
      const float* __restrict__ XT,
      const u16* __restrict__ IDX1, const u16* __restrict__ x2g, const u16* __restrict__ x3g,
      const u16* __restrict__ IDX4,
      const void* __restrict__ W1, const void* __restrict__ bn1,
      const void* __restrict__ W4, const void* __restrict__ bn4,
      const void* __restrict__ W5, const void* __restrict__ bn5,
      u32* __restrict__ hmaxk, float* __restrict__ hsum){
  if (FLAG[0] != (BF ? 1 : 0)) return;
  __shared__ float xs[PTS][512];                        // 16 KB: [x1|x2|x3|x4] per point
  __shared__ __align__(16) u16 x3nb[PTS][KNN][128];     // 40 KB
  __shared__ float xtn[PTS][21][3];
  __shared__ u16   idx1L[PTS][KNN], idx4L[PTS][KNN];
  __shared__ float W1s[384], bn1s[256], bn4s[1024];
  const int tid = threadIdx.x;
  const int g0 = blockIdx.x*PTS, b = g0 / NN, n0 = g0 - b*NN;

  for (int k = tid; k < PTS*KNN; k += 256){
    int pt = k/KNN, t = k - pt*KNN;
    idx1L[pt][t] = IDX1[(size_t)(g0+pt)*KNN + t];
    idx4L[pt][t] = IDX4[(size_t)(g0+pt)*KNN + t];
  }
  for (int k = tid; k < 384; k += 256) W1s[k] = wget<BF>(W1, k);
  if (tid < 256) bn1s[tid] = wget<BF>(bn1, tid);
  for (int k = tid; k < 1024; k += 256) bn4s[k] = wget<BF>(bn4, k);
  __syncthreads();

  // gather x3 neighbor rows (coalesced: 64 consecutive uints per row)
  u32* x3nbU = (u32*)x3nb;
  for (int k = tid; k < PTS*KNN*64; k += 256){
    int row = k >> 6, pr = k & 63;
    int pt = row/KNN, t = row - pt*KNN;
    const u32* src = (const u32*)(x3g + ((size_t)b*NN + idx4L[pt][t])*128);
    x3nbU[row*64 + pr] = src[pr];
  }
  for (int k = tid; k < PTS*21*3; k += 256){
    int row = k/3, c = k - row*3;
    int pt = row/21, slot = row - pt*21;
    int m = (slot < KNN) ? (int)idx1L[pt][slot] : (n0 + pt);
    xtn[pt][slot][c] = XT[((size_t)b*NN + m)*3 + c];
  }
  for (int k = tid; k < PTS*64; k += 256){
    int pt = k >> 6, c = k & 63;
    xs[pt][64 + c] = bu2f(x2g[(size_t)(g0+pt)*64 + c]);
  }
  for (int k = tid; k < PTS*128; k += 256){
    int pt = k >> 7, c = k & 127;
    xs[pt][128 + c] = bu2f(x3g[(size_t)(g0+pt)*128 + c]);
  }
  __syncthreads();

  // x1 recompute -> xs[pt][0:64)
  #pragma unroll
  for (int hh = 0; hh < PTS*64/256; ++hh){
    int k = tid + hh*256;
    int pt = k >> 6, o = k & 63;
    float wa0 = W1s[o*6], wa1 = W1s[o*6+1], wa2 = W1s[o*6+2];
    float wb0 = W1s[o*6+3], wb1 = W1s[o*6+4], wb2 = W1s[o*6+5];
    float pmax = -INFINITY;
    #pragma unroll
    for (int t = 0; t < KNN; ++t)
      pmax = fmaxf(pmax, xtn[pt][t][0]*wa0 + xtn[pt][t][1]*wa1 + xtn[pt][t][2]*wa2);
    float po = xtn[pt][20][0]*wa0 + xtn[pt][20][1]*wa1 + xtn[pt][20][2]*wa2;
    float qo = xtn[pt][20][0]*wb0 + xtn[pt][20][1]*wb1 + xtn[pt][20][2]*wb2;
    float h = pmax - po + qo;
    float sc = bn1s[o] / sqrtf(bn1s[192+o] + 1e-5f);
    h = (h - bn1s[128+o])*sc + bn1s[64+o];
    xs[pt][o] = lrelu(h);
  }
  __syncthreads();

  // x4 recompute -> xs[pt][256:512); thread = output channel o
  {
    const int o = tid;
    for (int pt = 0; pt < PTS; ++pt){
      float acc[21]; float accq = 0.f;
      #pragma unroll
      for (int s = 0; s < 21; ++s) acc[s] = 0.f;
      for (int cc = 0; cc < 128; cc += 8){
        float wa[8], wb[8];
        wload8<BF>(W4, (size_t)o*256 + cc, wa);
        wload8<BF>(W4, (size_t)o*256 + 128 + cc, wb);
        #pragma unroll
        for (int u = 0; u < 8; ++u){
          float xo = xs[pt][128 + cc + u];
          acc[20] += xo*wa[u]; accq += xo*wb[u];
        }
        #pragma unroll
        for (int s = 0; s < KNN; ++s){
          const uint4 ur = *(const uint4*)&x3nbU[(pt*KNN + s)*64 + (cc>>1)];
          acc[s] += lo16(ur.x)*wa[0] + hi16(ur.x)*wa[1] + lo16(ur.y)*wa[2] + hi16(ur.y)*wa[3]
                  + lo16(ur.z)*wa[4] + hi16(ur.z)*wa[5] + lo16(ur.w)*wa[6] + hi16(ur.w)*wa[7];
        }
      }
      float m = -INFINITY;
      #pragma unroll
      for (int s = 0; s < KNN; ++s) m = fmaxf(m, acc[s]);
      float h = m - acc[20] + accq;
      float sc = bn4s[o] / sqrtf(bn4s[768+o] + 1e-5f);
      h = (h - bn4s[512+o])*sc + bn4s[256+o];
      xs[pt][256 + o] = lrelu(h);
    }
  }
  __syncthreads();

  // W5 (1024x512) + bn5 + act + fused max/mean pooling
  {
    const int o = tid;
    #pragma unroll
    for (int jo = 0; jo < 4; ++jo){
      int out = jo*256 + o;
      float acc[PTS];
      #pragma unroll
      for (int pt = 0; pt < PTS; ++pt) acc[pt] = 0.f;
      for (int cc = 0; cc < 512; cc += 8){
        float w[8];
        wload8<BF>(W5, (size_t)out*512 + cc, w);
        #pragma unroll
        for (int pt = 0; pt < PTS; ++pt){
          acc[pt] += xs[pt][cc]*w[0] + xs[pt][cc+1]*w[1] + xs[pt][cc+2]*w[2] + xs[pt][cc+3]*w[3]
                   + xs[pt][cc+4]*w[4] + xs[pt][cc+5]*w[5] + xs[pt][cc+6]*w[6] + xs[pt][cc+7]*w[7];
        }
      }
      float g = wget<BF>(bn5, out), be = wget<BF>(bn5, 1024+out),
            mu = wget<BF>(bn5, 2048+out), va = wget<BF>(bn5, 3072+out);
      float sc = g / sqrtf(va + 1e-5f);
      float lm = -INFINITY, ls = 0.f;
      #pragma unroll
      for (int pt = 0; pt < PTS; ++pt){
        float h = (acc[pt] - mu)*sc + be;
        h = lrelu(h);
        lm = fmaxf(lm, h); ls += h;
      }
      atomicMax(&hmaxk[b*1024 + out], f2key(lm));
      atomicAdd(&hsum[b*1024 + out], ls);
    }
  }
}

// ---------------- head: [max|mean] -> FC512 -> FC256 -> FC40 ------------------------
template<bool BF>
__global__ __launch_bounds__(512) void k_head(const int* __restrict__ FLAG,
                    const u32* __restrict__ hmaxk, const float* __restrict__ hsum,
                    const void* __restrict__ Wl1, const void* __restrict__ bn6,
                    const void* __restrict__ Wl2, const void* __restrict__ bl2,
                    const void* __restrict__ bn7,
                    const void* __restrict__ Wl3, const void* __restrict__ bl3,
                    void* __restrict__ out){
  if (FLAG[0] != (BF ? 1 : 0)) return;
  __shared__ float hc[2048];
  __shared__ float h2s[512];
  __shared__ float h3s[256];
  int b = blockIdx.x, tid = threadIdx.x;
  for (int k = tid; k < 1024; k += 512){
    hc[k]        = key2f(hmaxk[b*1024 + k]);
    hc[1024 + k] = hsum[b*1024 + k] * (1.0f/2048.0f);
  }
  __syncthreads();
  {
    float acc = 0.f;
    for (int cc = 0; cc < 2048; cc += 8){
      float w[8];
      wload8<BF>(Wl1, (size_t)tid*2048 + cc, w);
      #pragma unroll
      for (int u = 0; u < 8; ++u) acc += w[u]*hc[cc+u];
    }
    float g = wget<BF>(bn6, tid), be = wget<BF>(bn6, 512+tid),
          mu = wget<BF>(bn6, 1024+tid), va = wget<BF>(bn6, 1536+tid);
    float sc = g / sqrtf(va + 1e-5f);
    h2s[tid] = lrelu((acc - mu)*sc + be);
  }
  __syncthreads();
  if (tid < 256){
    float acc = 0.f;
    for (int cc = 0; cc < 512; cc += 8){
      float w[8];
      wload8<BF>(Wl2, (size_t)tid*512 + cc, w);
      #pragma unroll
      for (int u = 0; u < 8; ++u) acc += w[u]*h2s[cc+u];
    }
    acc += wget<BF>(bl2, tid);
    float g = wget<BF>(bn7, tid), be = wget<BF>(bn7, 256+tid),
          mu = wget<BF>(bn7, 512+tid), va = wget<BF>(bn7, 768+tid);
    float sc = g / sqrtf(va + 1e-5f);
    h3s[tid] = lrelu((acc - mu)*sc + be);
  }
  __syncthreads();
  if (tid < 40){
    float acc = 0.f;
    for (int cc = 0; cc < 256; cc += 8){
      float w[8];
      wload8<BF>(Wl3, (size_t)tid*256 + cc, w);
      #pragma unroll
      for (int u = 0; u < 8; ++u) acc += w[u]*h3s[cc+u];
    }
    acc += wget<BF>(bl3, tid);
    if (BF) ((u16*)out)[b*40 + tid] = f2bu(acc);
    else    ((float*)out)[b*40 + tid] = acc;
  }
}

extern "C" void kernel_launch(void* const* d_in, const int* in_sizes, int n_in,
                              void* d_out, int out_size, void* d_ws, size_t ws_size,
                              hipStream_t stream){
  const void* x   = d_in[0];
  const void* W1  = d_in[1];
  const void* bn1 = d_in[2];
  const void* W2  = d_in[3];
  const void* bn2 = d_in[4];
  const void* W3  = d_in[5];
  const void* bn3 = d_in[6];
  const void* W4  = d_in[7];
  const void* bn4 = d_in[8];
  const void* W5  = d_in[9];
  const void* bn5 = d_in[10];
  const void* Wl1 = d_in[11];
  const void* bn6 = d_in[12];
  const void* Wl2 = d_in[13];
  const void* bl2 = d_in[14];
  const void* bn7 = d_in[15];
  const void* Wl3 = d_in[16];
  const void* bl3 = d_in[17];

  // ---- workspace layout (bytes), total 15,859,968 — fits the known-safe 16.33 MB ----
  char* base = (char*)d_ws;
  int*   FLAG  = (int*)  (base + 0);            //      256 B
  float* XT    = (float*)(base + 256);          //  393,216 B  [P,3] fp32
  float* SQ    = (float*)(base + 393472);       //  131,072 B  [P] fp32
  u32*   HMAXK = (u32*)  (base + 524544);       //   65,536 B
  float* HSUM  = (float*)(base + 590080);       //   65,536 B
  u16*   IDX1  = (u16*)  (base + 655616);       // 1,310,720 B [P,20] u16
  u16*   IDX   = (u16*)  (base + 1966336);      // 1,310,720 B [P,20] u16 (stages 2..4)
  u16*   X2    = (u16*)  (base + 3277056);      // 4,194,304 B [P,64] bf16
  u16*   X3    = (u16*)  (base + 7471360);      // 8,388,608 B [P,128] bf16
  u16*   X1    = X3;                            // aliases X3: x1 dead before EC3 writes x3

  dim3 knnG(NN/64, BB);

  k_detect<<<1, 256, 0, stream>>>((const u16*)x, FLAG);

  k_prep<true ><<<PP/256, 256, 0, stream>>>(FLAG, x, XT, SQ, HMAXK, HSUM);
  k_prep<false><<<PP/256, 256, 0, stream>>>(FLAG, x, XT, SQ, HMAXK, HSUM);

  // EC1: XT (C=3) -> x1
  k_knn<3,128,false><<<knnG, 256, 0, stream>>>(XT, SQ, IDX1);
  k_ec1<true ><<<PP/4, 256, 0, stream>>>(FLAG, XT, IDX1, W1, bn1, X1);
  k_ec1<false><<<PP/4, 256, 0, stream>>>(FLAG, XT, IDX1, W1, bn1, X1);

  // EC2: x1 -> x2
  k_sq<64><<<PP/256, 256, 0, stream>>>(X1, SQ);
  k_knn<64,32,true><<<knnG, 256, 0, stream>>>(X1, SQ, IDX);
  k_ec_slab<64,true ><<<dim3(16, BB), 256, 0, stream>>>(FLAG, X1, IDX, W2, bn2, 64, X2);
  k_ec_slab<64,false><<<dim3(16, BB), 256, 0, stream>>>(FLAG, X1, IDX, W2, bn2, 64, X2);

  // EC3: x2 -> x3 (overwrites x1 region)
  k_sq<64><<<PP/256, 256, 0, stream>>>(X2, SQ);
  k_knn<64,32,true><<<knnG, 256, 0, stream>>>(X2, SQ, IDX);
  k_ec_slab<64,true ><<<dim3(32, BB), 256, 0, stream>>>(FLAG, X2, IDX, W3, bn3, 128, X3);
  k_ec_slab<64,false><<<dim3(32, BB), 256, 0, stream>>>(FLAG, X2, IDX, W3, bn3, 128, X3);

  // EC4 KNN only (x4 recomputed inside k_w5f)
  k_sq<128><<<PP/256, 256, 0, stream>>>(X3, SQ);
  k_knn<128,16,true><<<knnG, 256, 0, stream>>>(X3, SQ, IDX);

  // fused x1/x4 recompute + W5 + bn5 + act + global max/mean pooling
  k_w5f<true ><<<PP/PTS, 256, 0, stream>>>(FLAG, XT, IDX1, X2, X3, IDX,
                                           W1, bn1, W4, bn4, W5, bn5, HMAXK, HSUM);
  k_w5f<false><<<PP/PTS, 256, 0, stream>>>(FLAG, XT, IDX1, X2, X3, IDX,
                                           W1, bn1, W4, bn4, W5, bn5, HMAXK, HSUM);

  // head FCs
  k_head<true ><<<BB, 512, 0, stream>>>(FLAG, HMAXK, HSUM, Wl1, bn6, Wl2, bl2, bn7, Wl3, bl3, d_out);
  k_head<false><<<BB, 512, 0, stream>>>(FLAG, HMAXK, HSUM, Wl1, bn6, Wl2, bl2, bn7, Wl3, bl3, d_out);
}

// Round 6
// 8839.941 us; speedup vs baseline: 1.7117x; 1.2442x over previous
//
#include <hip/hip_runtime.h>
#include <hip/hip_bf16.h>

#define BB 16
#define NN 2048
#define PP (BB*NN)
#define KNN 20

typedef __hip_bfloat16 bf16;
typedef unsigned short u16;
typedef unsigned int u32;
typedef __attribute__((ext_vector_type(8))) short s8v;   // 8 bf16 = 4 VGPR (MFMA A/B frag)
typedef __attribute__((ext_vector_type(4))) float f4v;   // MFMA C/D frag

__device__ __forceinline__ float bu2f(u16 u){ return __uint_as_float(((u32)u) << 16); }
__device__ __forceinline__ float lo16(u32 u){ return __uint_as_float(u << 16); }
__device__ __forceinline__ float hi16(u32 u){ return __uint_as_float(u & 0xffff0000u); }
__device__ __forceinline__ u16 f2bu(float f){ bf16 h = __float2bfloat16(f); return *(u16*)&h; }
__device__ __forceinline__ float lrelu(float h){ return (h >= 0.f) ? h : 0.2f*h; }

// order-preserving float->uint map for atomicMax on floats
__device__ __forceinline__ u32 f2key(float f){
  u32 u = __float_as_uint(f);
  return (u & 0x80000000u) ? ~u : (u | 0x80000000u);
}
__device__ __forceinline__ float key2f(u32 k){
  u32 u = (k & 0x80000000u) ? (k & 0x7FFFFFFFu) : ~k;
  return __uint_as_float(u);
}

// dtype-generic weight accessors (BF: raw bf16 u16; else fp32)
template<bool BF> __device__ __forceinline__ float wget(const void* p, size_t i){
  return BF ? bu2f(((const u16*)p)[i]) : ((const float*)p)[i];
}
template<bool BF> __device__ __forceinline__ void wload8(const void* p, size_t base, float w[8]){
  if (BF){
    const uint4 u = *(const uint4*)((const u16*)p + base);
    w[0]=lo16(u.x); w[1]=hi16(u.x); w[2]=lo16(u.y); w[3]=hi16(u.y);
    w[4]=lo16(u.z); w[5]=hi16(u.z); w[6]=lo16(u.w); w[7]=hi16(u.w);
  } else {
    const float4* f = (const float4*)((const float*)p + base);
    float4 a = f[0], b = f[1];
    w[0]=a.x; w[1]=a.y; w[2]=a.z; w[3]=a.w; w[4]=b.x; w[5]=b.y; w[6]=b.z; w[7]=b.w;
  }
}

// ---------------- dtype detector: bf16 (1) vs fp32 (0) ------------------------------
__global__ void k_detect(const u16* __restrict__ xr, int* __restrict__ flag){
  __shared__ int cnt;
  if (threadIdx.x == 0) cnt = 0;
  __syncthreads();
  float v = bu2f(xr[threadIdx.x * 2]);
  float a = fabsf(v);
  int ok = (a > 1e-6f && a < 1e6f) ? 1 : 0;   // NaN/Inf -> 0
  atomicAdd(&cnt, ok);
  __syncthreads();
  if (threadIdx.x == 0) flag[0] = (cnt >= 160) ? 1 : 0;
}

// ---------------- prep: transpose x [B,3,N] -> XT [P,3] fp32, SQ, pool init ---------
template<bool BF>
__global__ void k_prep(const int* __restrict__ FLAG, const void* __restrict__ x,
                       float* __restrict__ XT, float* __restrict__ SQ,
                       u32* __restrict__ hmaxk, float* __restrict__ hsum){
  if (FLAG[0] != (BF ? 1 : 0)) return;
  int i = blockIdx.x*256 + threadIdx.x;
  if (i >= PP) return;
  int b = i / NN, n = i - b*NN;
  float s = 0.f;
  #pragma unroll
  for (int c = 0; c < 3; ++c){
    float v = wget<BF>(x, ((size_t)b*3 + c)*NN + n);
    XT[(size_t)i*3 + c] = v;
    s += v*v;
  }
  SQ[i] = s;
  if (i < BB*1024){ hmaxk[i] = 0u; hsum[i] = 0.f; }
}

// ---------------- SQ[i] = sum_c x[i,c]^2 (ascending, internal bf16 features) --------
template<int Cin>
__global__ void k_sq(const u16* __restrict__ xin, float* __restrict__ SQ){
  int i = blockIdx.x*256 + threadIdx.x;
  if (i >= PP) return;
  const u32* r = (const u32*)(xin + (size_t)i*Cin);
  float s = 0.f;
  for (int c = 0; c < Cin/2; ++c){
    u32 u = r[c];
    float a = lo16(u), b = hi16(u);
    s += a*a; s += b*b;
  }
  SQ[i] = s;
}

// ---------------- stage-1 KNN (C=3 fp32): block = 64 queries x 4 seg-waves ----------
template<int C, int TC>
__global__ __launch_bounds__(256) void k_knn(const float* __restrict__ xin,
                                             const float* __restrict__ SQ,
                                             u16* __restrict__ IDX){
  __shared__ float cf[4][TC*C];
  __shared__ float csqv[4][TC];
  __shared__ float tv[4][KNN][64];
  __shared__ u16   ti[4][KNN][64];
  const int tid = threadIdx.x, w = tid >> 6, lane = tid & 63;
  const int b = blockIdx.y;
  const int q = blockIdx.x*64 + lane;
  const int j0 = w * 512;

  float qf[C];
  const float* xq = xin + ((size_t)b*NN + q)*C;
  #pragma unroll
  for (int c = 0; c < C; ++c) qf[c] = xq[c];
  const float sqq = SQ[b*NN + q];

  #pragma unroll
  for (int t = 0; t < KNN; ++t){ tv[w][t][lane] = -INFINITY; ti[w][t][lane] = 0; }
  float minv = -INFINITY;

  for (int t0 = 0; t0 < 512; t0 += TC){
    __syncthreads();
    const float* src = xin + ((size_t)b*NN + j0 + t0)*C;
    for (int k = lane; k < TC*C; k += 64) cf[w][k] = src[k];
    for (int k = lane; k < TC; k += 64) csqv[w][k] = SQ[b*NN + j0 + t0 + k];
    __syncthreads();
    for (int j = 0; j < TC; ++j){
      float dot = 0.f;
      #pragma unroll
      for (int c = 0; c < C; ++c) dot += qf[c]*cf[w][j*C + c];
      float d = 2.f*dot - sqq - csqv[w][j];
      if (d > minv){
        int t = KNN-1;
        while (t > 0){
          float pv = tv[w][t-1][lane];
          if (pv >= d) break;
          tv[w][t][lane] = pv; ti[w][t][lane] = ti[w][t-1][lane];
          --t;
        }
        tv[w][t][lane] = d; ti[w][t][lane] = (u16)(j0 + t0 + j);
        minv = tv[w][KNN-1][lane];
      }
    }
  }
  __syncthreads();
  if (tid < 64){
    int p0=0,p1=0,p2=0,p3=0;
    u16* op = IDX + ((size_t)b*NN + q)*KNN;
    for (int t = 0; t < KNN; ++t){
      float v0 = tv[0][p0][tid], v1 = tv[1][p1][tid], v2 = tv[2][p2][tid], v3 = tv[3][p3][tid];
      int bs = 0; float bv = v0;
      if (v1 > bv){ bv = v1; bs = 1; }
      if (v2 > bv){ bv = v2; bs = 2; }
      if (v3 > bv){ bv = v3; bs = 3; }
      u16 bi;
      if      (bs == 0){ bi = ti[0][p0][tid]; p0++; }
      else if (bs == 1){ bi = ti[1][p1][tid]; p1++; }
      else if (bs == 2){ bi = ti[2][p2][tid]; p2++; }
      else             { bi = ti[3][p3][tid]; p3++; }
      op[t] = bi;
    }
  }
}

// ---------------- MFMA KNN (stages 2-4, bf16 features) ------------------------------
// Block = 4 waves: wave w -> queries q0+(w>>1)*16 .. +15, candidate segment (w&1)*1024.
// Per tile: A = 16 candidates, B = 16 queries, D[cand][query] via mfma 16x16x32 bf16.
// Lane (quad=lane>>4, n=lane&15): query q0+..+n, candidates ct+quad*4+r (r=0..3).
// Per-lane exact top-20 lists in LDS; exact 8-way merge (2 seg x 4 quad) at the end.
template<int C>
__global__ __launch_bounds__(256) void k_knn_mfma(const u16* __restrict__ xin,
                                                  const float* __restrict__ SQ,
                                                  u16* __restrict__ IDX){
  __shared__ float tv[KNN][256];
  __shared__ u16   ti[KNN][256];
  const int tid = threadIdx.x, w = tid >> 6, lane = tid & 63;
  const int quad = lane >> 4, n = lane & 15;
  const int seg = w & 1, qg = w >> 1;
  const int b = blockIdx.y;
  const int q = blockIdx.x*32 + qg*16 + n;       // this lane's query
  const int cbase = seg * (NN/2);
  const u16* Xb = xin + (size_t)b*NN*C;

  // B-frags: query features (fixed for the whole scan)
  s8v bfrag[C/32];
  #pragma unroll
  for (int kc = 0; kc < C/32; ++kc)
    bfrag[kc] = *(const s8v*)(Xb + (size_t)q*C + kc*32 + quad*8);
  const float sqq = SQ[b*NN + q];

  #pragma unroll
  for (int t = 0; t < KNN; ++t){ tv[t][tid] = -INFINITY; ti[t][tid] = 0; }
  float minv = -INFINITY;

  // prefetch first candidate tile (A-frags)
  s8v afr[C/32], afn[C/32];
  #pragma unroll
  for (int kc = 0; kc < C/32; ++kc)
    afr[kc] = *(const s8v*)(Xb + (size_t)(cbase + n)*C + kc*32 + quad*8);

  for (int ct = cbase; ct < cbase + NN/2; ct += 16){
    int ctn = (ct + 16 < cbase + NN/2) ? (ct + 16) : cbase;   // wrap: dummy prefetch
    #pragma unroll
    for (int kc = 0; kc < C/32; ++kc)
      afn[kc] = *(const s8v*)(Xb + (size_t)(ctn + n)*C + kc*32 + quad*8);
    f4v sqc = *(const f4v*)&SQ[b*NN + ct + quad*4];
    f4v acc = {0.f, 0.f, 0.f, 0.f};
    #pragma unroll
    for (int kc = 0; kc < C/32; ++kc)
      acc = __builtin_amdgcn_mfma_f32_16x16x32_bf16(afr[kc], bfrag[kc], acc, 0, 0, 0);
    #pragma unroll
    for (int r = 0; r < 4; ++r){
      float d = 2.f*acc[r] - sqq - sqc[r];
      if (d > minv){                   // strict >: later ties excluded (top_k stable)
        int t = KNN-1;
        while (t > 0){
          float pv = tv[t-1][tid];
          if (pv >= d) break;
          tv[t][tid] = pv; ti[t][tid] = ti[t-1][tid];
          --t;
        }
        tv[t][tid] = d; ti[t][tid] = (u16)(ct + quad*4 + r);
        minv = tv[KNN-1][tid];
      }
    }
    #pragma unroll
    for (int kc = 0; kc < C/32; ++kc) afr[kc] = afn[kc];
  }
  __syncthreads();

  // exact 8-way merge per query; ties -> smaller candidate index (top_k stable)
  if (tid < 32){
    int mn = tid & 15, mqg = tid >> 4;
    int mq = blockIdx.x*32 + mqg*16 + mn;
    int p[8] = {0,0,0,0,0,0,0,0};
    u16* op = IDX + ((size_t)b*NN + mq)*KNN;
    for (int t = 0; t < KNN; ++t){
      float bv = -INFINITY; int bs = 0; u16 bi = 0xFFFF;
      #pragma unroll
      for (int s = 0; s < 8; ++s){
        int col = mqg*128 + (s >> 2)*64 + (s & 3)*16 + mn;
        float v = tv[p[s]][col];
        u16  ii = ti[p[s]][col];
        if (v > bv || (v == bv && ii < bi)){ bv = v; bs = s; bi = ii; }
      }
      op[t] = bi; p[bs]++;
    }
  }
}

// ---------------- EC1 direct (C=3 -> O=64): block = 4 points x 64 channels ----------
template<bool BF>
__global__ __launch_bounds__(256) void k_ec1(const int* __restrict__ FLAG,
                    const float* __restrict__ XT,
                    const u16* __restrict__ IDX1, const void* __restrict__ W1,
                    const void* __restrict__ bn1, u16* __restrict__ x1out){
  if (FLAG[0] != (BF ? 1 : 0)) return;
  __shared__ float nbx[4][21][3];
  __shared__ float W1s[384];
  __shared__ float bn1s[256];
  __shared__ u16   idxL[4][KNN];
  const int tid = threadIdx.x;
  const int g0 = blockIdx.x*4, b = g0 / NN;
  for (int k = tid; k < 384; k += 256) W1s[k] = wget<BF>(W1, k);
  if (tid < 256) bn1s[tid] = wget<BF>(bn1, tid);
  if (tid < 80){ int pt = tid/KNN, t = tid%KNN; idxL[pt][t] = IDX1[(size_t)(g0+pt)*KNN + t]; }
  __syncthreads();
  for (int k = tid; k < 4*21*3; k += 256){
    int row = k/3, c = k - row*3;
    int pt = row/21, slot = row - pt*21;
    int m = (slot < KNN) ? (int)idxL[pt][slot] : (g0 + pt - b*NN);
    nbx[pt][slot][c] = XT[((size_t)b*NN + m)*3 + c];
  }
  __syncthreads();
  int pt = tid >> 6, o = tid & 63;
  float wa0 = W1s[o*6], wa1 = W1s[o*6+1], wa2 = W1s[o*6+2];
  float wb0 = W1s[o*6+3], wb1 = W1s[o*6+4], wb2 = W1s[o*6+5];
  float pmax = -INFINITY;
  #pragma unroll
  for (int t = 0; t < KNN; ++t)
    pmax = fmaxf(pmax, nbx[pt][t][0]*wa0 + nbx[pt][t][1]*wa1 + nbx[pt][t][2]*wa2);
  float po = nbx[pt][20][0]*wa0 + nbx[pt][20][1]*wa1 + nbx[pt][20][2]*wa2;
  float qo = nbx[pt][20][0]*wb0 + nbx[pt][20][1]*wb1 + nbx[pt][20][2]*wb2;
  float h = pmax - po + qo;
  float sc = bn1s[o] / sqrtf(bn1s[192+o] + 1e-5f);
  h = (h - bn1s[128+o])*sc + bn1s[64+o];
  x1out[(size_t)(g0+pt)*64 + o] = f2bu(lrelu(h));
}

// ---------------- EC slab (EC2/EC3): block = (4-out slab, batch); P in LDS ----------
template<int Cin, bool BF>
__global__ __launch_bounds__(256) void k_ec_slab(const int* __restrict__ FLAG,
                    const u16* __restrict__ xin,
                    const u16* __restrict__ idx, const void* __restrict__ W,
                    const void* __restrict__ bn, int O, u16* __restrict__ xout){
  if (FLAG[0] != (BF ? 1 : 0)) return;
  __shared__ float PS[NN][4];          // 32 KB
  __shared__ float Wa[4][Cin], Wb[4][Cin];
  __shared__ float bnp[16];
  const int b = blockIdx.y, o0 = blockIdx.x*4;
  const int tid = threadIdx.x;
  for (int k = tid; k < 4*2*Cin; k += 256){
    int r = k/(2*Cin), c = k - r*2*Cin;
    float v = wget<BF>(W, (size_t)(o0+r)*2*Cin + c);
    if (c < Cin) Wa[r][c] = v; else Wb[r][c-Cin] = v;
  }
  if (tid < 16){ int pidx = tid/4, j = tid%4; bnp[tid] = wget<BF>(bn, (size_t)pidx*O + o0 + j); }
  __syncthreads();

  float pown[8][4], qreg[8][4];
  #pragma unroll
  for (int rr = 0; rr < 8; ++rr){
    int r = tid + rr*256;
    const u32* xr = (const u32*)(xin + ((size_t)b*NN + r)*Cin);
    float p0=0,p1=0,p2=0,p3=0,q0=0,q1=0,q2=0,q3=0;
    for (int c2 = 0; c2 < Cin/2; ++c2){
      u32 u = xr[c2];
      float xa = lo16(u), xb = hi16(u);
      int c = 2*c2;
      p0 += xa*Wa[0][c]; p1 += xa*Wa[1][c]; p2 += xa*Wa[2][c]; p3 += xa*Wa[3][c];
      q0 += xa*Wb[0][c]; q1 += xa*Wb[1][c]; q2 += xa*Wb[2][c]; q3 += xa*Wb[3][c];
      p0 += xb*Wa[0][c+1]; p1 += xb*Wa[1][c+1]; p2 += xb*Wa[2][c+1]; p3 += xb*Wa[3][c+1];
      q0 += xb*Wb[0][c+1]; q1 += xb*Wb[1][c+1]; q2 += xb*Wb[2][c+1]; q3 += xb*Wb[3][c+1];
    }
    PS[r][0]=p0; PS[r][1]=p1; PS[r][2]=p2; PS[r][3]=p3;
    pown[rr][0]=p0; pown[rr][1]=p1; pown[rr][2]=p2; pown[rr][3]=p3;
    qreg[rr][0]=q0; qreg[rr][1]=q1; qreg[rr][2]=q2; qreg[rr][3]=q3;
  }
  __syncthreads();
  #pragma unroll
  for (int rr = 0; rr < 8; ++rr){
    int r = tid + rr*256;
    const u16* ip = idx + ((size_t)b*NN + r)*KNN;
    float m0=-INFINITY, m1=-INFINITY, m2=-INFINITY, m3=-INFINITY;
    for (int t = 0; t < KNN; ++t){
      int nb = ip[t];
      float4 pv = *(const float4*)&PS[nb][0];
      m0 = fmaxf(m0, pv.x); m1 = fmaxf(m1, pv.y);
      m2 = fmaxf(m2, pv.z); m3 = fmaxf(m3, pv.w);
    }
    float hv[4] = { m0 - pown[rr][0] + qreg[rr][0], m1 - pown[rr][1] + qreg[rr][1],
                    m2 - pown[rr][2] + qreg[rr][2], m3 - pown[rr][3] + qreg[rr][3] };
    u16* op = xout + ((size_t)b*NN + r)*O + o0;
    #pragma unroll
    for (int j = 0; j < 4; ++j){
      float sc = bnp[j] / sqrtf(bnp[12+j] + 1e-5f);
      float h = (hv[j] - bnp[8+j])*sc + bnp[4+j];
      op[j] = f2bu(lrelu(h));
    }
  }
}

// ---------------- fused: x1-recompute + x4-recompute + W5 + BN5 + act + pooling -----
#define PTS 8
template<bool BF>
__global__ __launch_bounds__(256) void k_w5f(const int* __restrict__ FLAG,
      const float* __restrict__ XT,
      const u16* __restrict__ IDX1, const u16* __restrict__ x2g, const u16* __restrict__ x3g,
      const u16* __restrict__ IDX4,
      const void* __restrict__ W1, const void* __restrict__ bn1,
      const void* __restrict__ W4, const void* __restrict__ bn4,
      const void* __restrict__ W5, const void* __restrict__ bn5,
      u32* __restrict__ hmaxk, float* __restrict__ hsum){
  if (FLAG[0] != (BF ? 1 : 0)) return;
  __shared__ float xs[PTS][512];
  __shared__ __align__(16) u16 x3nb[PTS][KNN][128];
  __shared__ float xtn[PTS][21][3];
  __shared__ u16   idx1L[PTS][KNN], idx4L[PTS][KNN];
  __shared__ float W1s[384], bn1s[256], bn4s[1024];
  const int tid = threadIdx.x;
  const int g0 = blockIdx.x*PTS, b = g0 / NN, n0 = g0 - b*NN;

  for (int k = tid; k < PTS*KNN; k += 256){
    int pt = k/KNN, t = k - pt*KNN;
    idx1L[pt][t] = IDX1[(size_t)(g0+pt)*KNN + t];
    idx4L[pt][t] = IDX4[(size_t)(g0+pt)*KNN + t];
  }
  for (int k = tid; k < 384; k += 256) W1s[k] = wget<BF>(W1, k);
  if (tid < 256) bn1s[tid] = wget<BF>(bn1, tid);
  for (int k = tid; k < 1024; k += 256) bn4s[k] = wget<BF>(bn4, k);
  __syncthreads();

  u32* x3nbU = (u32*)x3nb;
  for (int k = tid; k < PTS*KNN*64; k += 256){
    int row = k >> 6, pr = k & 63;
    int pt = row/KNN, t = row - pt*KNN;
    const u32* src = (const u32*)(x3g + ((size_t)b*NN + idx4L[pt][t])*128);
    x3nbU[row*64 + pr] = src[pr];
  }
  for (int k = tid; k < PTS*21*3; k += 256){
    int row = k/3, c = k - row*3;
    int pt = row/21, slot = row - pt*21;
    int m = (slot < KNN) ? (int)idx1L[pt][slot] : (n0 + pt);
    xtn[pt][slot][c] = XT[((size_t)b*NN + m)*3 + c];
  }
  for (int k = tid; k < PTS*64; k += 256){
    int pt = k >> 6, c = k & 63;
    xs[pt][64 + c] = bu2f(x2g[(size_t)(g0+pt)*64 + c]);
  }
  for (int k = tid; k < PTS*128; k += 256){
    int pt = k >> 7, c = k & 127;
    xs[pt][128 + c] = bu2f(x3g[(size_t)(g0+pt)*128 + c]);
  }
  __syncthreads();

  #pragma unroll
  for (int hh = 0; hh < PTS*64/256; ++hh){
    int k = tid + hh*256;
    int pt = k >> 6, o = k & 63;
    float wa0 = W1s[o*6], wa1 = W1s[o*6+1], wa2 = W1s[o*6+2];
    float wb0 = W1s[o*6+3], wb1 = W1s[o*6+4], wb2 = W1s[o*6+5];
    float pmax = -INFINITY;
    #pragma unroll
    for (int t = 0; t < KNN; ++t)
      pmax = fmaxf(pmax, xtn[pt][t][0]*wa0 + xtn[pt][t][1]*wa1 + xtn[pt][t][2]*wa2);
    float po = xtn[pt][20][0]*wa0 + xtn[pt][20][1]*wa1 + xtn[pt][20][2]*wa2;
    float qo = xtn[pt][20][0]*wb0 + xtn[pt][20][1]*wb1 + xtn[pt][20][2]*wb2;
    float h = pmax - po + qo;
    float sc = bn1s[o] / sqrtf(bn1s[192+o] + 1e-5f);
    h = (h - bn1s[128+o])*sc + bn1s[64+o];
    xs[pt][o] = lrelu(h);
  }
  __syncthreads();

  {
    const int o = tid;
    for (int pt = 0; pt < PTS; ++pt){
      float acc[21]; float accq = 0.f;
      #pragma unroll
      for (int s = 0; s < 21; ++s) acc[s] = 0.f;
      for (int cc = 0; cc < 128; cc += 8){
        float wa[8], wb[8];
        wload8<BF>(W4, (size_t)o*256 + cc, wa);
        wload8<BF>(W4, (size_t)o*256 + 128 + cc, wb);
        #pragma unroll
        for (int u = 0; u < 8; ++u){
          float xo = xs[pt][128 + cc + u];
          acc[20] += xo*wa[u]; accq += xo*wb[u];
        }
        #pragma unroll
        for (int s = 0; s < KNN; ++s){
          const uint4 ur = *(const uint4*)&x3nbU[(pt*KNN + s)*64 + (cc>>1)];
          acc[s] += lo16(ur.x)*wa[0] + hi16(ur.x)*wa[1] + lo16(ur.y)*wa[2] + hi16(ur.y)*wa[3]
                  + lo16(ur.z)*wa[4] + hi16(ur.z)*wa[5] + lo16(ur.w)*wa[6] + hi16(ur.w)*wa[7];
        }
      }
      float m = -INFINITY;
      #pragma unroll
      for (int s = 0; s < KNN; ++s) m = fmaxf(m, acc[s]);
      float h = m - acc[20] + accq;
      float sc = bn4s[o] / sqrtf(bn4s[768+o] + 1e-5f);
      h = (h - bn4s[512+o])*sc + bn4s[256+o];
      xs[pt][256 + o] = lrelu(h);
    }
  }
  __syncthreads();

  {
    const int o = tid;
    #pragma unroll
    for (int jo = 0; jo < 4; ++jo){
      int out = jo*256 + o;
      float acc[PTS];
      #pragma unroll
      for (int pt = 0; pt < PTS; ++pt) acc[pt] = 0.f;
      for (int cc = 0; cc < 512; cc += 8){
        float w[8];
        wload8<BF>(W5, (size_t)out*512 + cc, w);
        #pragma unroll
        for (int pt = 0; pt < PTS; ++pt){
          acc[pt] += xs[pt][cc]*w[0] + xs[pt][cc+1]*w[1] + xs[pt][cc+2]*w[2] + xs[pt][cc+3]*w[3]
                   + xs[pt][cc+4]*w[4] + xs[pt][cc+5]*w[5] + xs[pt][cc+6]*w[6] + xs[pt][cc+7]*w[7];
        }
      }
      float g = wget<BF>(bn5, out), be = wget<BF>(bn5, 1024+out),
            mu = wget<BF>(bn5, 2048+out), va = wget<BF>(bn5, 3072+out);
      float sc = g / sqrtf(va + 1e-5f);
      float lm = -INFINITY, ls = 0.f;
      #pragma unroll
      for (int pt = 0; pt < PTS; ++pt){
        float h = (acc[pt] - mu)*sc + be;
        h = lrelu(h);
        lm = fmaxf(lm, h); ls += h;
      }
      atomicMax(&hmaxk[b*1024 + out], f2key(lm));
      atomicAdd(&hsum[b*1024 + out], ls);
    }
  }
}

// ---------------- head: [max|mean] -> FC512 -> FC256 -> FC40 ------------------------
template<bool BF>
__global__ __launch_bounds__(512) void k_head(const int* __restrict__ FLAG,
                    const u32* __restrict__ hmaxk, const float* __restrict__ hsum,
                    const void* __restrict__ Wl1, const void* __restrict__ bn6,
                    const void* __restrict__ Wl2, const void* __restrict__ bl2,
                    const void* __restrict__ bn7,
                    const void* __restrict__ Wl3, const void* __restrict__ bl3,
                    void* __restrict__ out){
  if (FLAG[0] != (BF ? 1 : 0)) return;
  __shared__ float hc[2048];
  __shared__ float h2s[512];
  __shared__ float h3s[256];
  int b = blockIdx.x, tid = threadIdx.x;
  for (int k = tid; k < 1024; k += 512){
    hc[k]        = key2f(hmaxk[b*1024 + k]);
    hc[1024 + k] = hsum[b*1024 + k] * (1.0f/2048.0f);
  }
  __syncthreads();
  {
    float acc = 0.f;
    for (int cc = 0; cc < 2048; cc += 8){
      float w[8];
      wload8<BF>(Wl1, (size_t)tid*2048 + cc, w);
      #pragma unroll
      for (int u = 0; u < 8; ++u) acc += w[u]*hc[cc+u];
    }
    float g = wget<BF>(bn6, tid), be = wget<BF>(bn6, 512+tid),
          mu = wget<BF>(bn6, 1024+tid), va = wget<BF>(bn6, 1536+tid);
    float sc = g / sqrtf(va + 1e-5f);
    h2s[tid] = lrelu((acc - mu)*sc + be);
  }
  __syncthreads();
  if (tid < 256){
    float acc = 0.f;
    for (int cc = 0; cc < 512; cc += 8){
      float w[8];
      wload8<BF>(Wl2, (size_t)tid*512 + cc, w);
      #pragma unroll
      for (int u = 0; u < 8; ++u) acc += w[u]*h2s[cc+u];
    }
    acc += wget<BF>(bl2, tid);
    float g = wget<BF>(bn7, tid), be = wget<BF>(bn7, 256+tid),
          mu = wget<BF>(bn7, 512+tid), va = wget<BF>(bn7, 768+tid);
    float sc = g / sqrtf(va + 1e-5f);
    h3s[tid] = lrelu((acc - mu)*sc + be);
  }
  __syncthreads();
  if (tid < 40){
    float acc = 0.f;
    for (int cc = 0; cc < 256; cc += 8){
      float w[8];
      wload8<BF>(Wl3, (size_t)tid*256 + cc, w);
      #pragma unroll
      for (int u = 0; u < 8; ++u) acc += w[u]*h3s[cc+u];
    }
    acc += wget<BF>(bl3, tid);
    if (BF) ((u16*)out)[b*40 + tid] = f2bu(acc);
    else    ((float*)out)[b*40 + tid] = acc;
  }
}

extern "C" void kernel_launch(void* const* d_in, const int* in_sizes, int n_in,
                              void* d_out, int out_size, void* d_ws, size_t ws_size,
                              hipStream_t stream){
  const void* x   = d_in[0];
  const void* W1  = d_in[1];
  const void* bn1 = d_in[2];
  const void* W2  = d_in[3];
  const void* bn2 = d_in[4];
  const void* W3  = d_in[5];
  const void* bn3 = d_in[6];
  const void* W4  = d_in[7];
  const void* bn4 = d_in[8];
  const void* W5  = d_in[9];
  const void* bn5 = d_in[10];
  const void* Wl1 = d_in[11];
  const void* bn6 = d_in[12];
  const void* Wl2 = d_in[13];
  const void* bl2 = d_in[14];
  const void* bn7 = d_in[15];
  const void* Wl3 = d_in[16];
  const void* bl3 = d_in[17];

  // ---- workspace layout (bytes), total 15,859,968 — fits the known-safe 16.33 MB ----
  char* base = (char*)d_ws;
  int*   FLAG  = (int*)  (base + 0);            //      256 B
  float* XT    = (float*)(base + 256);          //  393,216 B  [P,3] fp32
  float* SQ    = (float*)(base + 393472);       //  131,072 B  [P] fp32
  u32*   HMAXK = (u32*)  (base + 524544);       //   65,536 B
  float* HSUM  = (float*)(base + 590080);       //   65,536 B
  u16*   IDX1  = (u16*)  (base + 655616);       // 1,310,720 B [P,20] u16
  u16*   IDX   = (u16*)  (base + 1966336);      // 1,310,720 B [P,20] u16 (stages 2..4)
  u16*   X2    = (u16*)  (base + 3277056);      // 4,194,304 B [P,64] bf16
  u16*   X3    = (u16*)  (base + 7471360);      // 8,388,608 B [P,128] bf16
  u16*   X1    = X3;                            // aliases X3: x1 dead before EC3 writes x3

  dim3 knnG1(NN/64, BB);      // stage-1 scalar KNN
  dim3 knnGM(NN/32, BB);      // MFMA KNN: 32 queries/block, 2 cand segments

  k_detect<<<1, 256, 0, stream>>>((const u16*)x, FLAG);

  k_prep<true ><<<PP/256, 256, 0, stream>>>(FLAG, x, XT, SQ, HMAXK, HSUM);
  k_prep<false><<<PP/256, 256, 0, stream>>>(FLAG, x, XT, SQ, HMAXK, HSUM);

  // EC1: XT (C=3) -> x1
  k_knn<3,128><<<knnG1, 256, 0, stream>>>(XT, SQ, IDX1);
  k_ec1<true ><<<PP/4, 256, 0, stream>>>(FLAG, XT, IDX1, W1, bn1, X1);
  k_ec1<false><<<PP/4, 256, 0, stream>>>(FLAG, XT, IDX1, W1, bn1, X1);

  // EC2: x1 -> x2
  k_sq<64><<<PP/256, 256, 0, stream>>>(X1, SQ);
  k_knn_mfma<64><<<knnGM, 256, 0, stream>>>(X1, SQ, IDX);
  k_ec_slab<64,true ><<<dim3(16, BB), 256, 0, stream>>>(FLAG, X1, IDX, W2, bn2, 64, X2);
  k_ec_slab<64,false><<<dim3(16, BB), 256, 0, stream>>>(FLAG, X1, IDX, W2, bn2, 64, X2);

  // EC3: x2 -> x3 (overwrites x1 region)
  k_sq<64><<<PP/256, 256, 0, stream>>>(X2, SQ);
  k_knn_mfma<64><<<knnGM, 256, 0, stream>>>(X2, SQ, IDX);
  k_ec_slab<64,true ><<<dim3(32, BB), 256, 0, stream>>>(FLAG, X2, IDX, W3, bn3, 128, X3);
  k_ec_slab<64,false><<<dim3(32, BB), 256, 0, stream>>>(FLAG, X2, IDX, W3, bn3, 128, X3);

  // EC4 KNN only (x4 recomputed inside k_w5f)
  k_sq<128><<<PP/256, 256, 0, stream>>>(X3, SQ);
  k_knn_mfma<128><<<knnGM, 256, 0, stream>>>(X3, SQ, IDX);

  // fused x1/x4 recompute + W5 + bn5 + act + global max/mean pooling
  k_w5f<true ><<<PP/PTS, 256, 0, stream>>>(FLAG, XT, IDX1, X2, X3, IDX,
                                           W1, bn1, W4, bn4, W5, bn5, HMAXK, HSUM);
  k_w5f<false><<<PP/PTS, 256, 0, stream>>>(FLAG, XT, IDX1, X2, X3, IDX,
                                           W1, bn1, W4, bn4, W5, bn5, HMAXK, HSUM);

  // head FCs
  k_head<true ><<<BB, 512, 0, stream>>>(FLAG, HMAXK, HSUM, Wl1, bn6, Wl2, bl2, bn7, Wl3, bl3, d_out);
  k_head<false><<<BB, 512, 0, stream>>>(FLAG, HMAXK, HSUM, Wl1, bn6, Wl2, bl2, bn7, Wl3, bl3, d_out);
}

// Round 7
// 7718.644 us; speedup vs baseline: 1.9603x; 1.1453x over previous
//
#include <hip/hip_runtime.h>
#include <hip/hip_bf16.h>

#define BB 16
#define NN 2048
#define PP (BB*NN)
#define KNN 20

typedef __hip_bfloat16 bf16;
typedef unsigned short u16;
typedef unsigned int u32;
typedef __attribute__((ext_vector_type(8))) short s8v;   // 8 bf16 = 4 VGPR (MFMA A/B frag)
typedef __attribute__((ext_vector_type(4))) float f4v;   // MFMA C/D frag

__device__ __forceinline__ float bu2f(u16 u){ return __uint_as_float(((u32)u) << 16); }
__device__ __forceinline__ float lo16(u32 u){ return __uint_as_float(u << 16); }
__device__ __forceinline__ float hi16(u32 u){ return __uint_as_float(u & 0xffff0000u); }
__device__ __forceinline__ u16 f2bu(float f){ bf16 h = __float2bfloat16(f); return *(u16*)&h; }
__device__ __forceinline__ float lrelu(float h){ return (h >= 0.f) ? h : 0.2f*h; }

__device__ __forceinline__ u32 f2key(float f){
  u32 u = __float_as_uint(f);
  return (u & 0x80000000u) ? ~u : (u | 0x80000000u);
}
__device__ __forceinline__ float key2f(u32 k){
  u32 u = (k & 0x80000000u) ? (k & 0x7FFFFFFFu) : ~k;
  return __uint_as_float(u);
}

template<bool BF> __device__ __forceinline__ float wget(const void* p, size_t i){
  return BF ? bu2f(((const u16*)p)[i]) : ((const float*)p)[i];
}
template<bool BF> __device__ __forceinline__ void wload8(const void* p, size_t base, float w[8]){
  if (BF){
    const uint4 u = *(const uint4*)((const u16*)p + base);
    w[0]=lo16(u.x); w[1]=hi16(u.x); w[2]=lo16(u.y); w[3]=hi16(u.y);
    w[4]=lo16(u.z); w[5]=hi16(u.z); w[6]=lo16(u.w); w[7]=hi16(u.w);
  } else {
    const float4* f = (const float4*)((const float*)p + base);
    float4 a = f[0], b = f[1];
    w[0]=a.x; w[1]=a.y; w[2]=a.z; w[3]=a.w; w[4]=b.x; w[5]=b.y; w[6]=b.z; w[7]=b.w;
  }
}

__device__ __forceinline__ f4v mfma16(s8v a, s8v b, f4v c){
  return __builtin_amdgcn_mfma_f32_16x16x32_bf16(a, b, c, 0, 0, 0);
}

// load 8 weights as hi/lo bf16 fragments (lo = residual; exact-weight MFMA via 2 ops)
template<bool BF> __device__ __forceinline__ void loadFragHL(const void* p, size_t base,
                                                             s8v& hi, s8v& lo){
  if (BF){
    hi = *(const s8v*)((const u16*)p + base);
  } else {
    float w[8]; wload8<false>(p, base, w);
    #pragma unroll
    for (int i = 0; i < 8; ++i){
      u16 hb = f2bu(w[i]);
      hi[i] = (short)hb;
      lo[i] = (short)f2bu(w[i] - bu2f(hb));
    }
  }
}
// hi/lo frags of (p[bb..] - p[ba..])
template<bool BF> __device__ __forceinline__ void loadDiffHL(const void* p, size_t ba, size_t bb,
                                                             s8v& hi, s8v& lo){
  float wa[8], wb[8];
  wload8<BF>(p, ba, wa); wload8<BF>(p, bb, wb);
  #pragma unroll
  for (int i = 0; i < 8; ++i){
    float d = wb[i] - wa[i];
    u16 hb = f2bu(d);
    hi[i] = (short)hb;
    lo[i] = (short)f2bu(d - bu2f(hb));
  }
}

// ---------------- dtype detector: bf16 (1) vs fp32 (0) ------------------------------
__global__ void k_detect(const u16* __restrict__ xr, int* __restrict__ flag){
  __shared__ int cnt;
  if (threadIdx.x == 0) cnt = 0;
  __syncthreads();
  float v = bu2f(xr[threadIdx.x * 2]);
  float a = fabsf(v);
  int ok = (a > 1e-6f && a < 1e6f) ? 1 : 0;
  atomicAdd(&cnt, ok);
  __syncthreads();
  if (threadIdx.x == 0) flag[0] = (cnt >= 160) ? 1 : 0;
}

// ---------------- prep: transpose x [B,3,N] -> XT [P,3] fp32, SQ, pool init ---------
template<bool BF>
__global__ void k_prep(const int* __restrict__ FLAG, const void* __restrict__ x,
                       float* __restrict__ XT, float* __restrict__ SQ,
                       u32* __restrict__ hmaxk, float* __restrict__ hsum){
  if (FLAG[0] != (BF ? 1 : 0)) return;
  int i = blockIdx.x*256 + threadIdx.x;
  if (i >= PP) return;
  int b = i / NN, n = i - b*NN;
  float s = 0.f;
  #pragma unroll
  for (int c = 0; c < 3; ++c){
    float v = wget<BF>(x, ((size_t)b*3 + c)*NN + n);
    XT[(size_t)i*3 + c] = v;
    s += v*v;
  }
  SQ[i] = s;
  if (i < BB*1024){ hmaxk[i] = 0u; hsum[i] = 0.f; }
}

// ---------------- SQ[i] = sum_c x[i,c]^2 -------------------------------------------
template<int Cin>
__global__ void k_sq(const u16* __restrict__ xin, float* __restrict__ SQ){
  int i = blockIdx.x*256 + threadIdx.x;
  if (i >= PP) return;
  const u32* r = (const u32*)(xin + (size_t)i*Cin);
  float s = 0.f;
  for (int c = 0; c < Cin/2; ++c){
    u32 u = r[c];
    float a = lo16(u), b = hi16(u);
    s += a*a; s += b*b;
  }
  SQ[i] = s;
}

// ---------------- stage-1 KNN (C=3 fp32): block = 64 queries x 4 seg-waves ----------
template<int C, int TC>
__global__ __launch_bounds__(256) void k_knn(const float* __restrict__ xin,
                                             const float* __restrict__ SQ,
                                             u16* __restrict__ IDX){
  __shared__ float cf[4][TC*C];
  __shared__ float csqv[4][TC];
  __shared__ float tv[4][KNN][64];
  __shared__ u16   ti[4][KNN][64];
  const int tid = threadIdx.x, w = tid >> 6, lane = tid & 63;
  const int b = blockIdx.y;
  const int q = blockIdx.x*64 + lane;
  const int j0 = w * 512;

  float qf[C];
  const float* xq = xin + ((size_t)b*NN + q)*C;
  #pragma unroll
  for (int c = 0; c < C; ++c) qf[c] = xq[c];
  const float sqq = SQ[b*NN + q];

  #pragma unroll
  for (int t = 0; t < KNN; ++t){ tv[w][t][lane] = -INFINITY; ti[w][t][lane] = 0; }
  float minv = -INFINITY;

  for (int t0 = 0; t0 < 512; t0 += TC){
    __syncthreads();
    const float* src = xin + ((size_t)b*NN + j0 + t0)*C;
    for (int k = lane; k < TC*C; k += 64) cf[w][k] = src[k];
    for (int k = lane; k < TC; k += 64) csqv[w][k] = SQ[b*NN + j0 + t0 + k];
    __syncthreads();
    for (int j = 0; j < TC; ++j){
      float dot = 0.f;
      #pragma unroll
      for (int c = 0; c < C; ++c) dot += qf[c]*cf[w][j*C + c];
      float d = 2.f*dot - sqq - csqv[w][j];
      if (d > minv){
        int t = KNN-1;
        while (t > 0){
          float pv = tv[w][t-1][lane];
          if (pv >= d) break;
          tv[w][t][lane] = pv; ti[w][t][lane] = ti[w][t-1][lane];
          --t;
        }
        tv[w][t][lane] = d; ti[w][t][lane] = (u16)(j0 + t0 + j);
        minv = tv[w][KNN-1][lane];
      }
    }
  }
  __syncthreads();
  if (tid < 64){
    int p0=0,p1=0,p2=0,p3=0;
    u16* op = IDX + ((size_t)b*NN + q)*KNN;
    for (int t = 0; t < KNN; ++t){
      float v0 = tv[0][p0][tid], v1 = tv[1][p1][tid], v2 = tv[2][p2][tid], v3 = tv[3][p3][tid];
      int bs = 0; float bv = v0;
      if (v1 > bv){ bv = v1; bs = 1; }
      if (v2 > bv){ bv = v2; bs = 2; }
      if (v3 > bv){ bv = v3; bs = 3; }
      u16 bi;
      if      (bs == 0){ bi = ti[0][p0][tid]; p0++; }
      else if (bs == 1){ bi = ti[1][p1][tid]; p1++; }
      else if (bs == 2){ bi = ti[2][p2][tid]; p2++; }
      else             { bi = ti[3][p3][tid]; p3++; }
      op[t] = bi;
    }
  }
}

// ---------------- MFMA KNN (stages 2-4, bf16 features) ------------------------------
template<int C>
__global__ __launch_bounds__(256) void k_knn_mfma(const u16* __restrict__ xin,
                                                  const float* __restrict__ SQ,
                                                  u16* __restrict__ IDX){
  __shared__ float tv[KNN][256];
  __shared__ u16   ti[KNN][256];
  const int tid = threadIdx.x, w = tid >> 6, lane = tid & 63;
  const int quad = lane >> 4, n = lane & 15;
  const int seg = w & 1, qg = w >> 1;
  const int b = blockIdx.y;
  const int q = blockIdx.x*32 + qg*16 + n;
  const int cbase = seg * (NN/2);
  const u16* Xb = xin + (size_t)b*NN*C;

  s8v bfrag[C/32];
  #pragma unroll
  for (int kc = 0; kc < C/32; ++kc)
    bfrag[kc] = *(const s8v*)(Xb + (size_t)q*C + kc*32 + quad*8);
  const float sqq = SQ[b*NN + q];

  #pragma unroll
  for (int t = 0; t < KNN; ++t){ tv[t][tid] = -INFINITY; ti[t][tid] = 0; }
  float minv = -INFINITY;

  s8v afr[C/32], afn[C/32];
  #pragma unroll
  for (int kc = 0; kc < C/32; ++kc)
    afr[kc] = *(const s8v*)(Xb + (size_t)(cbase + n)*C + kc*32 + quad*8);

  for (int ct = cbase; ct < cbase + NN/2; ct += 16){
    int ctn = (ct + 16 < cbase + NN/2) ? (ct + 16) : cbase;
    #pragma unroll
    for (int kc = 0; kc < C/32; ++kc)
      afn[kc] = *(const s8v*)(Xb + (size_t)(ctn + n)*C + kc*32 + quad*8);
    f4v sqc = *(const f4v*)&SQ[b*NN + ct + quad*4];
    f4v acc = {0.f, 0.f, 0.f, 0.f};
    #pragma unroll
    for (int kc = 0; kc < C/32; ++kc)
      acc = mfma16(afr[kc], bfrag[kc], acc);
    #pragma unroll
    for (int r = 0; r < 4; ++r){
      float d = 2.f*acc[r] - sqq - sqc[r];
      if (d > minv){
        int t = KNN-1;
        while (t > 0){
          float pv = tv[t-1][tid];
          if (pv >= d) break;
          tv[t][tid] = pv; ti[t][tid] = ti[t-1][tid];
          --t;
        }
        tv[t][tid] = d; ti[t][tid] = (u16)(ct + quad*4 + r);
        minv = tv[KNN-1][tid];
      }
    }
    #pragma unroll
    for (int kc = 0; kc < C/32; ++kc) afr[kc] = afn[kc];
  }
  __syncthreads();

  if (tid < 32){
    int mn = tid & 15, mqg = tid >> 4;
    int mq = blockIdx.x*32 + mqg*16 + mn;
    int p[8] = {0,0,0,0,0,0,0,0};
    u16* op = IDX + ((size_t)b*NN + mq)*KNN;
    for (int t = 0; t < KNN; ++t){
      float bv = -INFINITY; int bs = 0; u16 bi = 0xFFFF;
      #pragma unroll
      for (int s = 0; s < 8; ++s){
        int col = mqg*128 + (s >> 2)*64 + (s & 3)*16 + mn;
        float v = tv[p[s]][col];
        u16  ii = ti[p[s]][col];
        if (v > bv || (v == bv && ii < bi)){ bv = v; bs = s; bi = ii; }
      }
      op[t] = bi; p[bs]++;
    }
  }
}

// ---------------- EC1 direct (C=3 -> O=64): block = 4 points x 64 channels ----------
template<bool BF>
__global__ __launch_bounds__(256) void k_ec1(const int* __restrict__ FLAG,
                    const float* __restrict__ XT,
                    const u16* __restrict__ IDX1, const void* __restrict__ W1,
                    const void* __restrict__ bn1, u16* __restrict__ x1out){
  if (FLAG[0] != (BF ? 1 : 0)) return;
  __shared__ float nbx[4][21][3];
  __shared__ float W1s[384];
  __shared__ float bn1s[256];
  __shared__ u16   idxL[4][KNN];
  const int tid = threadIdx.x;
  const int g0 = blockIdx.x*4, b = g0 / NN;
  for (int k = tid; k < 384; k += 256) W1s[k] = wget<BF>(W1, k);
  if (tid < 256) bn1s[tid] = wget<BF>(bn1, tid);
  if (tid < 80){ int pt = tid/KNN, t = tid%KNN; idxL[pt][t] = IDX1[(size_t)(g0+pt)*KNN + t]; }
  __syncthreads();
  for (int k = tid; k < 4*21*3; k += 256){
    int row = k/3, c = k - row*3;
    int pt = row/21, slot = row - pt*21;
    int m = (slot < KNN) ? (int)idxL[pt][slot] : (g0 + pt - b*NN);
    nbx[pt][slot][c] = XT[((size_t)b*NN + m)*3 + c];
  }
  __syncthreads();
  int pt = tid >> 6, o = tid & 63;
  float wa0 = W1s[o*6], wa1 = W1s[o*6+1], wa2 = W1s[o*6+2];
  float wb0 = W1s[o*6+3], wb1 = W1s[o*6+4], wb2 = W1s[o*6+5];
  float pmax = -INFINITY;
  #pragma unroll
  for (int t = 0; t < KNN; ++t)
    pmax = fmaxf(pmax, nbx[pt][t][0]*wa0 + nbx[pt][t][1]*wa1 + nbx[pt][t][2]*wa2);
  float po = nbx[pt][20][0]*wa0 + nbx[pt][20][1]*wa1 + nbx[pt][20][2]*wa2;
  float qo = nbx[pt][20][0]*wb0 + nbx[pt][20][1]*wb1 + nbx[pt][20][2]*wb2;
  float h = pmax - po + qo;
  float sc = bn1s[o] / sqrtf(bn1s[192+o] + 1e-5f);
  h = (h - bn1s[128+o])*sc + bn1s[64+o];
  x1out[(size_t)(g0+pt)*64 + o] = f2bu(lrelu(h));
}

// ---------------- EC slab (EC2/EC3): block = (4-out slab, batch); P in LDS ----------
template<int Cin, bool BF>
__global__ __launch_bounds__(256) void k_ec_slab(const int* __restrict__ FLAG,
                    const u16* __restrict__ xin,
                    const u16* __restrict__ idx, const void* __restrict__ W,
                    const void* __restrict__ bn, int O, u16* __restrict__ xout){
  if (FLAG[0] != (BF ? 1 : 0)) return;
  __shared__ float PS[NN][4];
  __shared__ float Wa[4][Cin], Wb[4][Cin];
  __shared__ float bnp[16];
  const int b = blockIdx.y, o0 = blockIdx.x*4;
  const int tid = threadIdx.x;
  for (int k = tid; k < 4*2*Cin; k += 256){
    int r = k/(2*Cin), c = k - r*2*Cin;
    float v = wget<BF>(W, (size_t)(o0+r)*2*Cin + c);
    if (c < Cin) Wa[r][c] = v; else Wb[r][c-Cin] = v;
  }
  if (tid < 16){ int pidx = tid/4, j = tid%4; bnp[tid] = wget<BF>(bn, (size_t)pidx*O + o0 + j); }
  __syncthreads();

  float pown[8][4], qreg[8][4];
  #pragma unroll
  for (int rr = 0; rr < 8; ++rr){
    int r = tid + rr*256;
    const u32* xr = (const u32*)(xin + ((size_t)b*NN + r)*Cin);
    float p0=0,p1=0,p2=0,p3=0,q0=0,q1=0,q2=0,q3=0;
    for (int c2 = 0; c2 < Cin/2; ++c2){
      u32 u = xr[c2];
      float xa = lo16(u), xb = hi16(u);
      int c = 2*c2;
      p0 += xa*Wa[0][c]; p1 += xa*Wa[1][c]; p2 += xa*Wa[2][c]; p3 += xa*Wa[3][c];
      q0 += xa*Wb[0][c]; q1 += xa*Wb[1][c]; q2 += xa*Wb[2][c]; q3 += xa*Wb[3][c];
      p0 += xb*Wa[0][c+1]; p1 += xb*Wa[1][c+1]; p2 += xb*Wa[2][c+1]; p3 += xb*Wa[3][c+1];
      q0 += xb*Wb[0][c+1]; q1 += xb*Wb[1][c+1]; q2 += xb*Wb[2][c+1]; q3 += xb*Wb[3][c+1];
    }
    PS[r][0]=p0; PS[r][1]=p1; PS[r][2]=p2; PS[r][3]=p3;
    pown[rr][0]=p0; pown[rr][1]=p1; pown[rr][2]=p2; pown[rr][3]=p3;
    qreg[rr][0]=q0; qreg[rr][1]=q1; qreg[rr][2]=q2; qreg[rr][3]=q3;
  }
  __syncthreads();
  #pragma unroll
  for (int rr = 0; rr < 8; ++rr){
    int r = tid + rr*256;
    const u16* ip = idx + ((size_t)b*NN + r)*KNN;
    float m0=-INFINITY, m1=-INFINITY, m2=-INFINITY, m3=-INFINITY;
    for (int t = 0; t < KNN; ++t){
      int nb = ip[t];
      float4 pv = *(const float4*)&PS[nb][0];
      m0 = fmaxf(m0, pv.x); m1 = fmaxf(m1, pv.y);
      m2 = fmaxf(m2, pv.z); m3 = fmaxf(m3, pv.w);
    }
    float hv[4] = { m0 - pown[rr][0] + qreg[rr][0], m1 - pown[rr][1] + qreg[rr][1],
                    m2 - pown[rr][2] + qreg[rr][2], m3 - pown[rr][3] + qreg[rr][3] };
    u16* op = xout + ((size_t)b*NN + r)*O + o0;
    #pragma unroll
    for (int j = 0; j < 4; ++j){
      float sc = bnp[j] / sqrtf(bnp[12+j] + 1e-5f);
      float h = (hv[j] - bnp[8+j])*sc + bnp[4+j];
      op[j] = f2bu(lrelu(h));
    }
  }
}

// ---------------- fused MFMA: x1 + x4 recompute + W5 + BN5 + act + pooling ----------
// Block = 8 points, 4 waves. x4: D[nbrow][out] 16x16x32 tiles, row-max via shfl;
// -P_self+Q_self folded into one MFMA with B' = Wb-Wa. W5: A-frags hoisted, B streamed
// hi/lo (exact fp32 weights). Pooling: reg-reduce + shfl_xor(16) + quad0 atomics.
#define PTS 8
template<bool BF>
__global__ __launch_bounds__(256, 2) void k_w5f(const int* __restrict__ FLAG,
      const float* __restrict__ XT,
      const u16* __restrict__ IDX1, const u16* __restrict__ x2g, const u16* __restrict__ x3g,
      const u16* __restrict__ IDX4,
      const void* __restrict__ W1, const void* __restrict__ bn1,
      const void* __restrict__ W4, const void* __restrict__ bn4,
      const void* __restrict__ W5, const void* __restrict__ bn5,
      u32* __restrict__ hmaxk, float* __restrict__ hsum){
  if (FLAG[0] != (BF ? 1 : 0)) return;
  __shared__ __align__(16) u16 ANu[PTS*24*136];   // rows: 0-19 nb, 20-23 self; stride 136 (bank de-alias)
  __shared__ __align__(16) u16 xsu[PTS*520];      // [x1|x2|x3|x4] bf16, stride 520
  __shared__ float xtn[PTS][21][3];
  __shared__ u16   idx1L[PTS][KNN], idx4L[PTS][KNN];
  __shared__ float W1s[384], bn1s[256], bn4s[1024];
  const int tid = threadIdx.x, wv = tid >> 6, lane = tid & 63;
  const int quad = lane >> 4, n = lane & 15;
  const int g0 = blockIdx.x*PTS, b = g0 / NN, n0 = g0 - b*NN;

  for (int k = tid; k < PTS*KNN; k += 256){
    int pt = k/KNN, t = k - pt*KNN;
    idx1L[pt][t] = IDX1[(size_t)(g0+pt)*KNN + t];
    idx4L[pt][t] = IDX4[(size_t)(g0+pt)*KNN + t];
  }
  for (int k = tid; k < 384; k += 256) W1s[k] = wget<BF>(W1, k);
  if (tid < 256) bn1s[tid] = wget<BF>(bn1, tid);
  for (int k = tid; k < 1024; k += 256) bn4s[k] = wget<BF>(bn4, k);
  __syncthreads();

  // gather AN (u32 copies, coalesced 256B rows)
  u32* ANw = (u32*)ANu;
  for (int k = tid; k < PTS*24*64; k += 256){
    int row = k >> 6, pr = k & 63;
    int pt = row/24, r = row - pt*24;
    int m = (r < KNN) ? (int)idx4L[pt][r] : (n0 + pt);
    ANw[(pt*24 + r)*68 + pr] = ((const u32*)(x3g + ((size_t)b*NN + m)*128))[pr];
  }
  for (int k = tid; k < PTS*21*3; k += 256){
    int row = k/3, c = k - row*3;
    int pt = row/21, slot = row - pt*21;
    int m = (slot < KNN) ? (int)idx1L[pt][slot] : (n0 + pt);
    xtn[pt][slot][c] = XT[((size_t)b*NN + m)*3 + c];
  }
  // x2 (cols 64-127) and x3-self (cols 128-255) straight bf16 copies
  u32* xsw = (u32*)xsu;
  for (int k = tid; k < PTS*32; k += 256){
    int pt = k >> 5, c2 = k & 31;
    xsw[pt*260 + 32 + c2] = ((const u32*)(x2g + (size_t)(g0+pt)*64))[c2];
  }
  for (int k = tid; k < PTS*64; k += 256){
    int pt = k >> 6, c2 = k & 63;
    xsw[pt*260 + 64 + c2] = ((const u32*)(x3g + (size_t)(g0+pt)*128))[c2];
  }
  __syncthreads();

  // x1 recompute (scalar, tiny) -> xsu cols 0..63
  #pragma unroll
  for (int hh = 0; hh < PTS*64/256; ++hh){
    int k = tid + hh*256;
    int pt = k >> 6, o = k & 63;
    float wa0 = W1s[o*6], wa1 = W1s[o*6+1], wa2 = W1s[o*6+2];
    float wb0 = W1s[o*6+3], wb1 = W1s[o*6+4], wb2 = W1s[o*6+5];
    float pmax = -INFINITY;
    #pragma unroll
    for (int t = 0; t < KNN; ++t)
      pmax = fmaxf(pmax, xtn[pt][t][0]*wa0 + xtn[pt][t][1]*wa1 + xtn[pt][t][2]*wa2);
    float po = xtn[pt][20][0]*wa0 + xtn[pt][20][1]*wa1 + xtn[pt][20][2]*wa2;
    float qo = xtn[pt][20][0]*wb0 + xtn[pt][20][1]*wb1 + xtn[pt][20][2]*wb2;
    float h = pmax - po + qo;
    float sc = bn1s[o] / sqrtf(bn1s[192+o] + 1e-5f);
    h = (h - bn1s[128+o])*sc + bn1s[64+o];
    xsu[pt*520 + o] = f2bu(lrelu(h));
  }

  // ---- x4 via MFMA: wave wv handles out-tiles wv*4 .. wv*4+3 ----
  {
    s8v aself[4];
    #pragma unroll
    for (int kc = 0; kc < 4; ++kc)
      aself[kc] = *(const s8v*)&ANu[((lane&7)*24 + 20)*136 + kc*32 + quad*8];

    for (int i = 0; i < 4; ++i){
      const int o0 = (wv*4 + i)*16;
      const size_t wrow = (size_t)(o0 + n)*256;
      s8v bah[4], bal[4], bdh[4], bdl[4];
      #pragma unroll
      for (int kc = 0; kc < 4; ++kc){
        loadFragHL<BF>(W4, wrow + kc*32 + quad*8, bah[kc], bal[kc]);
        loadDiffHL<BF>(W4, wrow + kc*32 + quad*8, wrow + 128 + kc*32 + quad*8, bdh[kc], bdl[kc]);
      }
      f4v accq = {0.f,0.f,0.f,0.f};
      #pragma unroll
      for (int kc = 0; kc < 4; ++kc){
        accq = mfma16(aself[kc], bdh[kc], accq);
        accq = mfma16(aself[kc], bdl[kc], accq);
      }
      #pragma unroll
      for (int pt = 0; pt < PTS; ++pt){
        s8v a0[4], a1[4];
        #pragma unroll
        for (int kc = 0; kc < 4; ++kc){
          a0[kc] = *(const s8v*)&ANu[(pt*24 + (lane&15))*136 + kc*32 + quad*8];
          a1[kc] = *(const s8v*)&ANu[(pt*24 + 16 + (lane&7))*136 + kc*32 + quad*8];
        }
        f4v c0 = {0.f,0.f,0.f,0.f}, c1 = {0.f,0.f,0.f,0.f};
        #pragma unroll
        for (int kc = 0; kc < 4; ++kc){
          c0 = mfma16(a0[kc], bah[kc], c0);
          c1 = mfma16(a1[kc], bah[kc], c1);
          if (!BF){
            c0 = mfma16(a0[kc], bal[kc], c0);
            c1 = mfma16(a1[kc], bal[kc], c1);
          }
        }
        float pm = fmaxf(fmaxf(fmaxf(c0[0],c0[1]), fmaxf(c0[2],c0[3])),
                         fmaxf(fmaxf(c1[0],c1[1]), fmaxf(c1[2],c1[3])));
        pm = fmaxf(pm, __shfl_xor(pm, 16));
        pm = fmaxf(pm, __shfl_xor(pm, 32));
        if (quad == (pt >> 2)){
          float h = pm + accq[pt & 3];
          int o = o0 + n;
          float sc = bn4s[o] / sqrtf(bn4s[768+o] + 1e-5f);
          h = (h - bn4s[512+o])*sc + bn4s[256+o];
          xsu[pt*520 + 256 + o] = f2bu(lrelu(h));
        }
      }
    }
  }
  __syncthreads();

  // ---- W5 via MFMA: wave wv handles out-tiles wv*16 .. +15 (outs o = nt*16+n) ----
  {
    s8v afr[16];
    #pragma unroll
    for (int kc = 0; kc < 16; ++kc)
      afr[kc] = *(const s8v*)&xsu[(lane&7)*520 + kc*32 + quad*8];

    for (int i = 0; i < 16; ++i){
      const int o = (wv*16 + i)*16 + n;
      const size_t wrow = (size_t)o * 512;
      f4v acc = {0.f,0.f,0.f,0.f};
      #pragma unroll
      for (int kc = 0; kc < 16; ++kc){
        s8v bh, bl;
        loadFragHL<BF>(W5, wrow + kc*32 + quad*8, bh, bl);
        acc = mfma16(afr[kc], bh, acc);
        if (!BF) acc = mfma16(afr[kc], bl, acc);
      }
      float g = wget<BF>(bn5, o), be = wget<BF>(bn5, 1024+o),
            mu = wget<BF>(bn5, 2048+o), va = wget<BF>(bn5, 3072+o);
      float sc = g / sqrtf(va + 1e-5f);
      float lm = -INFINITY, ls = 0.f;
      #pragma unroll
      for (int r = 0; r < 4; ++r){
        float h = (acc[r] - mu)*sc + be;
        h = lrelu(h);
        lm = fmaxf(lm, h); ls += h;
      }
      lm = fmaxf(lm, __shfl_xor(lm, 16));
      ls = ls + __shfl_xor(ls, 16);
      if (quad == 0){
        atomicMax(&hmaxk[b*1024 + o], f2key(lm));
        atomicAdd(&hsum[b*1024 + o], ls);
      }
    }
  }
}

// ---------------- head: [max|mean] -> FC512 -> FC256 -> FC40 ------------------------
template<bool BF>
__global__ __launch_bounds__(512) void k_head(const int* __restrict__ FLAG,
                    const u32* __restrict__ hmaxk, const float* __restrict__ hsum,
                    const void* __restrict__ Wl1, const void* __restrict__ bn6,
                    const void* __restrict__ Wl2, const void* __restrict__ bl2,
                    const void* __restrict__ bn7,
                    const void* __restrict__ Wl3, const void* __restrict__ bl3,
                    void* __restrict__ out){
  if (FLAG[0] != (BF ? 1 : 0)) return;
  __shared__ float hc[2048];
  __shared__ float h2s[512];
  __shared__ float h3s[256];
  int b = blockIdx.x, tid = threadIdx.x;
  for (int k = tid; k < 1024; k += 512){
    hc[k]        = key2f(hmaxk[b*1024 + k]);
    hc[1024 + k] = hsum[b*1024 + k] * (1.0f/2048.0f);
  }
  __syncthreads();
  {
    float acc = 0.f;
    for (int cc = 0; cc < 2048; cc += 8){
      float w[8];
      wload8<BF>(Wl1, (size_t)tid*2048 + cc, w);
      #pragma unroll
      for (int u = 0; u < 8; ++u) acc += w[u]*hc[cc+u];
    }
    float g = wget<BF>(bn6, tid), be = wget<BF>(bn6, 512+tid),
          mu = wget<BF>(bn6, 1024+tid), va = wget<BF>(bn6, 1536+tid);
    float sc = g / sqrtf(va + 1e-5f);
    h2s[tid] = lrelu((acc - mu)*sc + be);
  }
  __syncthreads();
  if (tid < 256){
    float acc = 0.f;
    for (int cc = 0; cc < 512; cc += 8){
      float w[8];
      wload8<BF>(Wl2, (size_t)tid*512 + cc, w);
      #pragma unroll
      for (int u = 0; u < 8; ++u) acc += w[u]*h2s[cc+u];
    }
    acc += wget<BF>(bl2, tid);
    float g = wget<BF>(bn7, tid), be = wget<BF>(bn7, 256+tid),
          mu = wget<BF>(bn7, 512+tid), va = wget<BF>(bn7, 768+tid);
    float sc = g / sqrtf(va + 1e-5f);
    h3s[tid] = lrelu((acc - mu)*sc + be);
  }
  __syncthreads();
  if (tid < 40){
    float acc = 0.f;
    for (int cc = 0; cc < 256; cc += 8){
      float w[8];
      wload8<BF>(Wl3, (size_t)tid*256 + cc, w);
      #pragma unroll
      for (int u = 0; u < 8; ++u) acc += w[u]*h3s[cc+u];
    }
    acc += wget<BF>(bl3, tid);
    if (BF) ((u16*)out)[b*40 + tid] = f2bu(acc);
    else    ((float*)out)[b*40 + tid] = acc;
  }
}

extern "C" void kernel_launch(void* const* d_in, const int* in_sizes, int n_in,
                              void* d_out, int out_size, void* d_ws, size_t ws_size,
                              hipStream_t stream){
  const void* x   = d_in[0];
  const void* W1  = d_in[1];
  const void* bn1 = d_in[2];
  const void* W2  = d_in[3];
  const void* bn2 = d_in[4];
  const void* W3  = d_in[5];
  const void* bn3 = d_in[6];
  const void* W4  = d_in[7];
  const void* bn4 = d_in[8];
  const void* W5  = d_in[9];
  const void* bn5 = d_in[10];
  const void* Wl1 = d_in[11];
  const void* bn6 = d_in[12];
  const void* Wl2 = d_in[13];
  const void* bl2 = d_in[14];
  const void* bn7 = d_in[15];
  const void* Wl3 = d_in[16];
  const void* bl3 = d_in[17];

  // ---- workspace layout (bytes), total 15,859,968 — fits the known-safe 16.33 MB ----
  char* base = (char*)d_ws;
  int*   FLAG  = (int*)  (base + 0);
  float* XT    = (float*)(base + 256);
  float* SQ    = (float*)(base + 393472);
  u32*   HMAXK = (u32*)  (base + 524544);
  float* HSUM  = (float*)(base + 590080);
  u16*   IDX1  = (u16*)  (base + 655616);
  u16*   IDX   = (u16*)  (base + 1966336);
  u16*   X2    = (u16*)  (base + 3277056);
  u16*   X3    = (u16*)  (base + 7471360);
  u16*   X1    = X3;                            // aliases X3: x1 dead before EC3 writes x3

  dim3 knnG1(NN/64, BB);
  dim3 knnGM(NN/32, BB);

  k_detect<<<1, 256, 0, stream>>>((const u16*)x, FLAG);

  k_prep<true ><<<PP/256, 256, 0, stream>>>(FLAG, x, XT, SQ, HMAXK, HSUM);
  k_prep<false><<<PP/256, 256, 0, stream>>>(FLAG, x, XT, SQ, HMAXK, HSUM);

  // EC1: XT (C=3) -> x1
  k_knn<3,128><<<knnG1, 256, 0, stream>>>(XT, SQ, IDX1);
  k_ec1<true ><<<PP/4, 256, 0, stream>>>(FLAG, XT, IDX1, W1, bn1, X1);
  k_ec1<false><<<PP/4, 256, 0, stream>>>(FLAG, XT, IDX1, W1, bn1, X1);

  // EC2: x1 -> x2
  k_sq<64><<<PP/256, 256, 0, stream>>>(X1, SQ);
  k_knn_mfma<64><<<knnGM, 256, 0, stream>>>(X1, SQ, IDX);
  k_ec_slab<64,true ><<<dim3(16, BB), 256, 0, stream>>>(FLAG, X1, IDX, W2, bn2, 64, X2);
  k_ec_slab<64,false><<<dim3(16, BB), 256, 0, stream>>>(FLAG, X1, IDX, W2, bn2, 64, X2);

  // EC3: x2 -> x3 (overwrites x1 region)
  k_sq<64><<<PP/256, 256, 0, stream>>>(X2, SQ);
  k_knn_mfma<64><<<knnGM, 256, 0, stream>>>(X2, SQ, IDX);
  k_ec_slab<64,true ><<<dim3(32, BB), 256, 0, stream>>>(FLAG, X2, IDX, W3, bn3, 128, X3);
  k_ec_slab<64,false><<<dim3(32, BB), 256, 0, stream>>>(FLAG, X2, IDX, W3, bn3, 128, X3);

  // EC4 KNN only (x4 recomputed inside k_w5f)
  k_sq<128><<<PP/256, 256, 0, stream>>>(X3, SQ);
  k_knn_mfma<128><<<knnGM, 256, 0, stream>>>(X3, SQ, IDX);

  // fused x1/x4 recompute + W5 + bn5 + act + global max/mean pooling (MFMA)
  k_w5f<true ><<<PP/PTS, 256, 0, stream>>>(FLAG, XT, IDX1, X2, X3, IDX,
                                           W1, bn1, W4, bn4, W5, bn5, HMAXK, HSUM);
  k_w5f<false><<<PP/PTS, 256, 0, stream>>>(FLAG, XT, IDX1, X2, X3, IDX,
                                           W1, bn1, W4, bn4, W5, bn5, HMAXK, HSUM);

  // head FCs
  k_head<true ><<<BB, 512, 0, stream>>>(FLAG, HMAXK, HSUM, Wl1, bn6, Wl2, bl2, bn7, Wl3, bl3, d_out);
  k_head<false><<<BB, 512, 0, stream>>>(FLAG, HMAXK, HSUM, Wl1, bn6, Wl2, bl2, bn7, Wl3, bl3, d_out);
}

// Round 8
// 5493.471 us; speedup vs baseline: 2.7543x; 1.4051x over previous
//
#include <hip/hip_runtime.h>
#include <hip/hip_bf16.h>

#define BB 16
#define NN 2048
#define PP (BB*NN)
#define KNN 20

typedef __hip_bfloat16 bf16;
typedef unsigned short u16;
typedef unsigned int u32;
typedef __attribute__((ext_vector_type(8))) short s8v;   // 8 bf16 = 4 VGPR (MFMA A/B frag)
typedef __attribute__((ext_vector_type(4))) float f4v;   // MFMA C/D frag

__device__ __forceinline__ float bu2f(u16 u){ return __uint_as_float(((u32)u) << 16); }
__device__ __forceinline__ float lo16(u32 u){ return __uint_as_float(u << 16); }
__device__ __forceinline__ float hi16(u32 u){ return __uint_as_float(u & 0xffff0000u); }
__device__ __forceinline__ u16 f2bu(float f){ bf16 h = __float2bfloat16(f); return *(u16*)&h; }
__device__ __forceinline__ float lrelu(float h){ return (h >= 0.f) ? h : 0.2f*h; }

__device__ __forceinline__ u32 f2key(float f){
  u32 u = __float_as_uint(f);
  return (u & 0x80000000u) ? ~u : (u | 0x80000000u);
}
__device__ __forceinline__ float key2f(u32 k){
  u32 u = (k & 0x80000000u) ? (k & 0x7FFFFFFFu) : ~k;
  return __uint_as_float(u);
}

template<bool BF> __device__ __forceinline__ float wget(const void* p, size_t i){
  return BF ? bu2f(((const u16*)p)[i]) : ((const float*)p)[i];
}
template<bool BF> __device__ __forceinline__ void wload8(const void* p, size_t base, float w[8]){
  if (BF){
    const uint4 u = *(const uint4*)((const u16*)p + base);
    w[0]=lo16(u.x); w[1]=hi16(u.x); w[2]=lo16(u.y); w[3]=hi16(u.y);
    w[4]=lo16(u.z); w[5]=hi16(u.z); w[6]=lo16(u.w); w[7]=hi16(u.w);
  } else {
    const float4* f = (const float4*)((const float*)p + base);
    float4 a = f[0], b = f[1];
    w[0]=a.x; w[1]=a.y; w[2]=a.z; w[3]=a.w; w[4]=b.x; w[5]=b.y; w[6]=b.z; w[7]=b.w;
  }
}

__device__ __forceinline__ f4v mfma16(s8v a, s8v b, f4v c){
  return __builtin_amdgcn_mfma_f32_16x16x32_bf16(a, b, c, 0, 0, 0);
}

// load 8 weights as hi/lo bf16 fragments (lo = residual; exact-weight MFMA via 2 ops)
template<bool BF> __device__ __forceinline__ void loadFragHL(const void* p, size_t base,
                                                             s8v& hi, s8v& lo){
  if (BF){
    hi = *(const s8v*)((const u16*)p + base);
  } else {
    float w[8]; wload8<false>(p, base, w);
    #pragma unroll
    for (int i = 0; i < 8; ++i){
      u16 hb = f2bu(w[i]);
      hi[i] = (short)hb;
      lo[i] = (short)f2bu(w[i] - bu2f(hb));
    }
  }
}
// hi/lo frags of (p[bb..] - p[ba..])
template<bool BF> __device__ __forceinline__ void loadDiffHL(const void* p, size_t ba, size_t bb,
                                                             s8v& hi, s8v& lo){
  float wa[8], wb[8];
  wload8<BF>(p, ba, wa); wload8<BF>(p, bb, wb);
  #pragma unroll
  for (int i = 0; i < 8; ++i){
    float d = wb[i] - wa[i];
    u16 hb = f2bu(d);
    hi[i] = (short)hb;
    lo[i] = (short)f2bu(d - bu2f(hb));
  }
}

// ---------------- dtype detector: bf16 (1) vs fp32 (0) ------------------------------
__global__ void k_detect(const u16* __restrict__ xr, int* __restrict__ flag){
  __shared__ int cnt;
  if (threadIdx.x == 0) cnt = 0;
  __syncthreads();
  float v = bu2f(xr[threadIdx.x * 2]);
  float a = fabsf(v);
  int ok = (a > 1e-6f && a < 1e6f) ? 1 : 0;
  atomicAdd(&cnt, ok);
  __syncthreads();
  if (threadIdx.x == 0) flag[0] = (cnt >= 160) ? 1 : 0;
}

// ---------------- prep: transpose x [B,3,N] -> XT [P,3] fp32, SQ, pool init ---------
template<bool BF>
__global__ void k_prep(const int* __restrict__ FLAG, const void* __restrict__ x,
                       float* __restrict__ XT, float* __restrict__ SQ,
                       u32* __restrict__ hmaxk, float* __restrict__ hsum){
  if (FLAG[0] != (BF ? 1 : 0)) return;
  int i = blockIdx.x*256 + threadIdx.x;
  if (i >= PP) return;
  int b = i / NN, n = i - b*NN;
  float s = 0.f;
  #pragma unroll
  for (int c = 0; c < 3; ++c){
    float v = wget<BF>(x, ((size_t)b*3 + c)*NN + n);
    XT[(size_t)i*3 + c] = v;
    s += v*v;
  }
  SQ[i] = s;
  if (i < BB*1024){ hmaxk[i] = 0u; hsum[i] = 0.f; }
}

// ---------------- SQ[i] = sum_c x[i,c]^2 -------------------------------------------
template<int Cin>
__global__ void k_sq(const u16* __restrict__ xin, float* __restrict__ SQ){
  int i = blockIdx.x*256 + threadIdx.x;
  if (i >= PP) return;
  const u32* r = (const u32*)(xin + (size_t)i*Cin);
  float s = 0.f;
  for (int c = 0; c < Cin/2; ++c){
    u32 u = r[c];
    float a = lo16(u), b = hi16(u);
    s += a*a; s += b*b;
  }
  SQ[i] = s;
}

// ---------------- stage-1 KNN (C=3 fp32): block = 64 queries x 4 seg-waves ----------
template<int C, int TC>
__global__ __launch_bounds__(256) void k_knn(const float* __restrict__ xin,
                                             const float* __restrict__ SQ,
                                             u16* __restrict__ IDX){
  __shared__ float cf[4][TC*C];
  __shared__ float csqv[4][TC];
  __shared__ float tv[4][KNN][64];
  __shared__ u16   ti[4][KNN][64];
  const int tid = threadIdx.x, w = tid >> 6, lane = tid & 63;
  const int b = blockIdx.y;
  const int q = blockIdx.x*64 + lane;
  const int j0 = w * 512;

  float qf[C];
  const float* xq = xin + ((size_t)b*NN + q)*C;
  #pragma unroll
  for (int c = 0; c < C; ++c) qf[c] = xq[c];
  const float sqq = SQ[b*NN + q];

  #pragma unroll
  for (int t = 0; t < KNN; ++t){ tv[w][t][lane] = -INFINITY; ti[w][t][lane] = 0; }
  float minv = -INFINITY;

  for (int t0 = 0; t0 < 512; t0 += TC){
    __syncthreads();
    const float* src = xin + ((size_t)b*NN + j0 + t0)*C;
    for (int k = lane; k < TC*C; k += 64) cf[w][k] = src[k];
    for (int k = lane; k < TC; k += 64) csqv[w][k] = SQ[b*NN + j0 + t0 + k];
    __syncthreads();
    for (int j = 0; j < TC; ++j){
      float dot = 0.f;
      #pragma unroll
      for (int c = 0; c < C; ++c) dot += qf[c]*cf[w][j*C + c];
      float d = 2.f*dot - sqq - csqv[w][j];
      if (d > minv){
        int t = KNN-1;
        while (t > 0){
          float pv = tv[w][t-1][lane];
          if (pv >= d) break;
          tv[w][t][lane] = pv; ti[w][t][lane] = ti[w][t-1][lane];
          --t;
        }
        tv[w][t][lane] = d; ti[w][t][lane] = (u16)(j0 + t0 + j);
        minv = tv[w][KNN-1][lane];
      }
    }
  }
  __syncthreads();
  if (tid < 64){
    int p0=0,p1=0,p2=0,p3=0;
    u16* op = IDX + ((size_t)b*NN + q)*KNN;
    for (int t = 0; t < KNN; ++t){
      float v0 = tv[0][p0][tid], v1 = tv[1][p1][tid], v2 = tv[2][p2][tid], v3 = tv[3][p3][tid];
      int bs = 0; float bv = v0;
      if (v1 > bv){ bv = v1; bs = 1; }
      if (v2 > bv){ bv = v2; bs = 2; }
      if (v3 > bv){ bv = v3; bs = 3; }
      u16 bi;
      if      (bs == 0){ bi = ti[0][p0][tid]; p0++; }
      else if (bs == 1){ bi = ti[1][p1][tid]; p1++; }
      else if (bs == 2){ bi = ti[2][p2][tid]; p2++; }
      else             { bi = ti[3][p3][tid]; p3++; }
      op[t] = bi;
    }
  }
}

// ---------------- MFMA KNN (stages 2-4, bf16 features) ------------------------------
template<int C>
__global__ __launch_bounds__(256) void k_knn_mfma(const u16* __restrict__ xin,
                                                  const float* __restrict__ SQ,
                                                  u16* __restrict__ IDX){
  __shared__ float tv[KNN][256];
  __shared__ u16   ti[KNN][256];
  const int tid = threadIdx.x, w = tid >> 6, lane = tid & 63;
  const int quad = lane >> 4, n = lane & 15;
  const int seg = w & 1, qg = w >> 1;
  const int b = blockIdx.y;
  const int q = blockIdx.x*32 + qg*16 + n;
  const int cbase = seg * (NN/2);
  const u16* Xb = xin + (size_t)b*NN*C;

  s8v bfrag[C/32];
  #pragma unroll
  for (int kc = 0; kc < C/32; ++kc)
    bfrag[kc] = *(const s8v*)(Xb + (size_t)q*C + kc*32 + quad*8);
  const float sqq = SQ[b*NN + q];

  #pragma unroll
  for (int t = 0; t < KNN; ++t){ tv[t][tid] = -INFINITY; ti[t][tid] = 0; }
  float minv = -INFINITY;

  s8v afr[C/32], afn[C/32];
  #pragma unroll
  for (int kc = 0; kc < C/32; ++kc)
    afr[kc] = *(const s8v*)(Xb + (size_t)(cbase + n)*C + kc*32 + quad*8);

  for (int ct = cbase; ct < cbase + NN/2; ct += 16){
    int ctn = (ct + 16 < cbase + NN/2) ? (ct + 16) : cbase;
    #pragma unroll
    for (int kc = 0; kc < C/32; ++kc)
      afn[kc] = *(const s8v*)(Xb + (size_t)(ctn + n)*C + kc*32 + quad*8);
    f4v sqc = *(const f4v*)&SQ[b*NN + ct + quad*4];
    f4v acc = {0.f, 0.f, 0.f, 0.f};
    #pragma unroll
    for (int kc = 0; kc < C/32; ++kc)
      acc = mfma16(afr[kc], bfrag[kc], acc);
    #pragma unroll
    for (int r = 0; r < 4; ++r){
      float d = 2.f*acc[r] - sqq - sqc[r];
      if (d > minv){
        int t = KNN-1;
        while (t > 0){
          float pv = tv[t-1][tid];
          if (pv >= d) break;
          tv[t][tid] = pv; ti[t][tid] = ti[t-1][tid];
          --t;
        }
        tv[t][tid] = d; ti[t][tid] = (u16)(ct + quad*4 + r);
        minv = tv[KNN-1][tid];
      }
    }
    #pragma unroll
    for (int kc = 0; kc < C/32; ++kc) afr[kc] = afn[kc];
  }
  __syncthreads();

  if (tid < 32){
    int mn = tid & 15, mqg = tid >> 4;
    int mq = blockIdx.x*32 + mqg*16 + mn;
    int p[8] = {0,0,0,0,0,0,0,0};
    u16* op = IDX + ((size_t)b*NN + mq)*KNN;
    for (int t = 0; t < KNN; ++t){
      float bv = -INFINITY; int bs = 0; u16 bi = 0xFFFF;
      #pragma unroll
      for (int s = 0; s < 8; ++s){
        int col = mqg*128 + (s >> 2)*64 + (s & 3)*16 + mn;
        float v = tv[p[s]][col];
        u16  ii = ti[p[s]][col];
        if (v > bv || (v == bv && ii < bi)){ bv = v; bs = s; bi = ii; }
      }
      op[t] = bi; p[bs]++;
    }
  }
}

// ---------------- EC1 direct (C=3 -> O=64): block = 4 points x 64 channels ----------
template<bool BF>
__global__ __launch_bounds__(256) void k_ec1(const int* __restrict__ FLAG,
                    const float* __restrict__ XT,
                    const u16* __restrict__ IDX1, const void* __restrict__ W1,
                    const void* __restrict__ bn1, u16* __restrict__ x1out){
  if (FLAG[0] != (BF ? 1 : 0)) return;
  __shared__ float nbx[4][21][3];
  __shared__ float W1s[384];
  __shared__ float bn1s[256];
  __shared__ u16   idxL[4][KNN];
  const int tid = threadIdx.x;
  const int g0 = blockIdx.x*4, b = g0 / NN;
  for (int k = tid; k < 384; k += 256) W1s[k] = wget<BF>(W1, k);
  if (tid < 256) bn1s[tid] = wget<BF>(bn1, tid);
  if (tid < 80){ int pt = tid/KNN, t = tid%KNN; idxL[pt][t] = IDX1[(size_t)(g0+pt)*KNN + t]; }
  __syncthreads();
  for (int k = tid; k < 4*21*3; k += 256){
    int row = k/3, c = k - row*3;
    int pt = row/21, slot = row - pt*21;
    int m = (slot < KNN) ? (int)idxL[pt][slot] : (g0 + pt - b*NN);
    nbx[pt][slot][c] = XT[((size_t)b*NN + m)*3 + c];
  }
  __syncthreads();
  int pt = tid >> 6, o = tid & 63;
  float wa0 = W1s[o*6], wa1 = W1s[o*6+1], wa2 = W1s[o*6+2];
  float wb0 = W1s[o*6+3], wb1 = W1s[o*6+4], wb2 = W1s[o*6+5];
  float pmax = -INFINITY;
  #pragma unroll
  for (int t = 0; t < KNN; ++t)
    pmax = fmaxf(pmax, nbx[pt][t][0]*wa0 + nbx[pt][t][1]*wa1 + nbx[pt][t][2]*wa2);
  float po = nbx[pt][20][0]*wa0 + nbx[pt][20][1]*wa1 + nbx[pt][20][2]*wa2;
  float qo = nbx[pt][20][0]*wb0 + nbx[pt][20][1]*wb1 + nbx[pt][20][2]*wb2;
  float h = pmax - po + qo;
  float sc = bn1s[o] / sqrtf(bn1s[192+o] + 1e-5f);
  h = (h - bn1s[128+o])*sc + bn1s[64+o];
  x1out[(size_t)(g0+pt)*64 + o] = f2bu(lrelu(h));
}

// ---------------- MFMA edgeconv (EC2/EC3): block = 16 points, 4 waves ---------------
// Gather 20 nb rows + 4 self rows per point (coalesced 128B rows) into LDS, then per
// out-tile: D[nbrow][out] = AN x Wa^T via 16x16x32 MFMA (hi/lo exact fp32 weights),
// row-max via shfl_xor(16,32); -P_self+Q_self folded as one MFMA with B' = Wb-Wa.
// Self rows in the max are no-ops (self is always in top-k). Cin fixed at 64.
template<int O_, bool BF>
__global__ __launch_bounds__(256, 2) void k_ec(const int* __restrict__ FLAG,
                    const u16* __restrict__ xin, const u16* __restrict__ idx,
                    const void* __restrict__ W, const void* __restrict__ bn,
                    u16* __restrict__ xout){
  if (FLAG[0] != (BF ? 1 : 0)) return;
  __shared__ __align__(16) u16 ANu[16*24*72];    // 55.3 KB; row stride 72 u16 (16B-aligned)
  __shared__ u16 idxL[16][KNN];
  const int tid = threadIdx.x, wv = tid >> 6, lane = tid & 63;
  const int quad = lane >> 4, n = lane & 15;
  const int g0 = blockIdx.x*16, b = g0 / NN, n0 = g0 - b*NN;

  for (int k = tid; k < 16*KNN; k += 256){
    int pt = k/KNN, t = k - pt*KNN;
    idxL[pt][t] = idx[(size_t)(g0+pt)*KNN + t];
  }
  __syncthreads();
  u32* ANw = (u32*)ANu;
  for (int k = tid; k < 384*32; k += 256){     // 384 rows x 32 u32 (coalesced per row)
    int row = k >> 5, pr = k & 31;
    int pt = row/24, r = row - pt*24;
    int m = (r < KNN) ? (int)idxL[pt][r] : (n0 + pt);
    ANw[row*36 + pr] = ((const u32*)(xin + ((size_t)b*NN + m)*64))[pr];
  }
  __syncthreads();

  s8v aself[2];
  #pragma unroll
  for (int kc = 0; kc < 2; ++kc)
    aself[kc] = *(const s8v*)&ANu[((lane&15)*24 + 20)*72 + kc*32 + quad*8];

  for (int tt = wv; tt < O_/16; tt += 4){
    const int o = tt*16 + n;
    s8v bah[2], bal[2], bdh[2], bdl[2];
    #pragma unroll
    for (int kc = 0; kc < 2; ++kc){
      loadFragHL<BF>(W, (size_t)o*128 + kc*32 + quad*8, bah[kc], bal[kc]);
      loadDiffHL<BF>(W, (size_t)o*128 + kc*32 + quad*8,
                        (size_t)o*128 + 64 + kc*32 + quad*8, bdh[kc], bdl[kc]);
    }
    f4v accq = {0.f,0.f,0.f,0.f};
    #pragma unroll
    for (int kc = 0; kc < 2; ++kc){
      accq = mfma16(aself[kc], bdh[kc], accq);
      accq = mfma16(aself[kc], bdl[kc], accq);
    }
    float g  = wget<BF>(bn, o),        be = wget<BF>(bn, O_+o),
          mu = wget<BF>(bn, 2*O_+o),   va = wget<BF>(bn, 3*O_+o);
    float sc = g / sqrtf(va + 1e-5f);

    #pragma unroll
    for (int pt = 0; pt < 16; ++pt){
      s8v a0[2], a1[2];
      #pragma unroll
      for (int kc = 0; kc < 2; ++kc){
        a0[kc] = *(const s8v*)&ANu[(pt*24 + (lane&15))*72 + kc*32 + quad*8];
        a1[kc] = *(const s8v*)&ANu[(pt*24 + 16 + (lane&7))*72 + kc*32 + quad*8];
      }
      f4v c0 = {0.f,0.f,0.f,0.f}, c1 = {0.f,0.f,0.f,0.f};
      #pragma unroll
      for (int kc = 0; kc < 2; ++kc){
        c0 = mfma16(a0[kc], bah[kc], c0);
        c1 = mfma16(a1[kc], bah[kc], c1);
        if (!BF){
          c0 = mfma16(a0[kc], bal[kc], c0);
          c1 = mfma16(a1[kc], bal[kc], c1);
        }
      }
      float pm = fmaxf(fmaxf(fmaxf(c0[0],c0[1]), fmaxf(c0[2],c0[3])),
                       fmaxf(fmaxf(c1[0],c1[1]), fmaxf(c1[2],c1[3])));
      pm = fmaxf(pm, __shfl_xor(pm, 16));
      pm = fmaxf(pm, __shfl_xor(pm, 32));
      if (quad == (pt >> 2)){
        float h = pm + accq[pt & 3];
        h = (h - mu)*sc + be;
        xout[(size_t)(g0+pt)*O_ + o] = f2bu(lrelu(h));
      }
    }
  }
}

// ---------------- fused MFMA: x1 + x4 recompute + W5 + BN5 + act + pooling ----------
#define PTS 8
template<bool BF>
__global__ __launch_bounds__(256, 2) void k_w5f(const int* __restrict__ FLAG,
      const float* __restrict__ XT,
      const u16* __restrict__ IDX1, const u16* __restrict__ x2g, const u16* __restrict__ x3g,
      const u16* __restrict__ IDX4,
      const void* __restrict__ W1, const void* __restrict__ bn1,
      const void* __restrict__ W4, const void* __restrict__ bn4,
      const void* __restrict__ W5, const void* __restrict__ bn5,
      u32* __restrict__ hmaxk, float* __restrict__ hsum){
  if (FLAG[0] != (BF ? 1 : 0)) return;
  __shared__ __align__(16) u16 ANu[PTS*24*136];
  __shared__ __align__(16) u16 xsu[PTS*520];
  __shared__ float xtn[PTS][21][3];
  __shared__ u16   idx1L[PTS][KNN], idx4L[PTS][KNN];
  __shared__ float W1s[384], bn1s[256], bn4s[1024];
  const int tid = threadIdx.x, wv = tid >> 6, lane = tid & 63;
  const int quad = lane >> 4, n = lane & 15;
  const int g0 = blockIdx.x*PTS, b = g0 / NN, n0 = g0 - b*NN;

  for (int k = tid; k < PTS*KNN; k += 256){
    int pt = k/KNN, t = k - pt*KNN;
    idx1L[pt][t] = IDX1[(size_t)(g0+pt)*KNN + t];
    idx4L[pt][t] = IDX4[(size_t)(g0+pt)*KNN + t];
  }
  for (int k = tid; k < 384; k += 256) W1s[k] = wget<BF>(W1, k);
  if (tid < 256) bn1s[tid] = wget<BF>(bn1, tid);
  for (int k = tid; k < 1024; k += 256) bn4s[k] = wget<BF>(bn4, k);
  __syncthreads();

  u32* ANw = (u32*)ANu;
  for (int k = tid; k < PTS*24*64; k += 256){
    int row = k >> 6, pr = k & 63;
    int pt = row/24, r = row - pt*24;
    int m = (r < KNN) ? (int)idx4L[pt][r] : (n0 + pt);
    ANw[(pt*24 + r)*68 + pr] = ((const u32*)(x3g + ((size_t)b*NN + m)*128))[pr];
  }
  for (int k = tid; k < PTS*21*3; k += 256){
    int row = k/3, c = k - row*3;
    int pt = row/21, slot = row - pt*21;
    int m = (slot < KNN) ? (int)idx1L[pt][slot] : (n0 + pt);
    xtn[pt][slot][c] = XT[((size_t)b*NN + m)*3 + c];
  }
  u32* xsw = (u32*)xsu;
  for (int k = tid; k < PTS*32; k += 256){
    int pt = k >> 5, c2 = k & 31;
    xsw[pt*260 + 32 + c2] = ((const u32*)(x2g + (size_t)(g0+pt)*64))[c2];
  }
  for (int k = tid; k < PTS*64; k += 256){
    int pt = k >> 6, c2 = k & 63;
    xsw[pt*260 + 64 + c2] = ((const u32*)(x3g + (size_t)(g0+pt)*128))[c2];
  }
  __syncthreads();

  #pragma unroll
  for (int hh = 0; hh < PTS*64/256; ++hh){
    int k = tid + hh*256;
    int pt = k >> 6, o = k & 63;
    float wa0 = W1s[o*6], wa1 = W1s[o*6+1], wa2 = W1s[o*6+2];
    float wb0 = W1s[o*6+3], wb1 = W1s[o*6+4], wb2 = W1s[o*6+5];
    float pmax = -INFINITY;
    #pragma unroll
    for (int t = 0; t < KNN; ++t)
      pmax = fmaxf(pmax, xtn[pt][t][0]*wa0 + xtn[pt][t][1]*wa1 + xtn[pt][t][2]*wa2);
    float po = xtn[pt][20][0]*wa0 + xtn[pt][20][1]*wa1 + xtn[pt][20][2]*wa2;
    float qo = xtn[pt][20][0]*wb0 + xtn[pt][20][1]*wb1 + xtn[pt][20][2]*wb2;
    float h = pmax - po + qo;
    float sc = bn1s[o] / sqrtf(bn1s[192+o] + 1e-5f);
    h = (h - bn1s[128+o])*sc + bn1s[64+o];
    xsu[pt*520 + o] = f2bu(lrelu(h));
  }

  {
    s8v aself[4];
    #pragma unroll
    for (int kc = 0; kc < 4; ++kc)
      aself[kc] = *(const s8v*)&ANu[((lane&7)*24 + 20)*136 + kc*32 + quad*8];

    for (int i = 0; i < 4; ++i){
      const int o0 = (wv*4 + i)*16;
      const size_t wrow = (size_t)(o0 + n)*256;
      s8v bah[4], bal[4], bdh[4], bdl[4];
      #pragma unroll
      for (int kc = 0; kc < 4; ++kc){
        loadFragHL<BF>(W4, wrow + kc*32 + quad*8, bah[kc], bal[kc]);
        loadDiffHL<BF>(W4, wrow + kc*32 + quad*8, wrow + 128 + kc*32 + quad*8, bdh[kc], bdl[kc]);
      }
      f4v accq = {0.f,0.f,0.f,0.f};
      #pragma unroll
      for (int kc = 0; kc < 4; ++kc){
        accq = mfma16(aself[kc], bdh[kc], accq);
        accq = mfma16(aself[kc], bdl[kc], accq);
      }
      #pragma unroll
      for (int pt = 0; pt < PTS; ++pt){
        s8v a0[4], a1[4];
        #pragma unroll
        for (int kc = 0; kc < 4; ++kc){
          a0[kc] = *(const s8v*)&ANu[(pt*24 + (lane&15))*136 + kc*32 + quad*8];
          a1[kc] = *(const s8v*)&ANu[(pt*24 + 16 + (lane&7))*136 + kc*32 + quad*8];
        }
        f4v c0 = {0.f,0.f,0.f,0.f}, c1 = {0.f,0.f,0.f,0.f};
        #pragma unroll
        for (int kc = 0; kc < 4; ++kc){
          c0 = mfma16(a0[kc], bah[kc], c0);
          c1 = mfma16(a1[kc], bah[kc], c1);
          if (!BF){
            c0 = mfma16(a0[kc], bal[kc], c0);
            c1 = mfma16(a1[kc], bal[kc], c1);
          }
        }
        float pm = fmaxf(fmaxf(fmaxf(c0[0],c0[1]), fmaxf(c0[2],c0[3])),
                         fmaxf(fmaxf(c1[0],c1[1]), fmaxf(c1[2],c1[3])));
        pm = fmaxf(pm, __shfl_xor(pm, 16));
        pm = fmaxf(pm, __shfl_xor(pm, 32));
        if (quad == (pt >> 2)){
          float h = pm + accq[pt & 3];
          int o = o0 + n;
          float sc = bn4s[o] / sqrtf(bn4s[768+o] + 1e-5f);
          h = (h - bn4s[512+o])*sc + bn4s[256+o];
          xsu[pt*520 + 256 + o] = f2bu(lrelu(h));
        }
      }
    }
  }
  __syncthreads();

  {
    s8v afr[16];
    #pragma unroll
    for (int kc = 0; kc < 16; ++kc)
      afr[kc] = *(const s8v*)&xsu[(lane&7)*520 + kc*32 + quad*8];

    for (int i = 0; i < 16; ++i){
      const int o = (wv*16 + i)*16 + n;
      const size_t wrow = (size_t)o * 512;
      f4v acc = {0.f,0.f,0.f,0.f};
      #pragma unroll
      for (int kc = 0; kc < 16; ++kc){
        s8v bh, bl;
        loadFragHL<BF>(W5, wrow + kc*32 + quad*8, bh, bl);
        acc = mfma16(afr[kc], bh, acc);
        if (!BF) acc = mfma16(afr[kc], bl, acc);
      }
      float g = wget<BF>(bn5, o), be = wget<BF>(bn5, 1024+o),
            mu = wget<BF>(bn5, 2048+o), va = wget<BF>(bn5, 3072+o);
      float sc = g / sqrtf(va + 1e-5f);
      float lm = -INFINITY, ls = 0.f;
      #pragma unroll
      for (int r = 0; r < 4; ++r){
        float h = (acc[r] - mu)*sc + be;
        h = lrelu(h);
        lm = fmaxf(lm, h); ls += h;
      }
      lm = fmaxf(lm, __shfl_xor(lm, 16));
      ls = ls + __shfl_xor(ls, 16);
      if (quad == 0){
        atomicMax(&hmaxk[b*1024 + o], f2key(lm));
        atomicAdd(&hsum[b*1024 + o], ls);
      }
    }
  }
}

// ---------------- head: [max|mean] -> FC512 -> FC256 -> FC40 ------------------------
template<bool BF>
__global__ __launch_bounds__(512) void k_head(const int* __restrict__ FLAG,
                    const u32* __restrict__ hmaxk, const float* __restrict__ hsum,
                    const void* __restrict__ Wl1, const void* __restrict__ bn6,
                    const void* __restrict__ Wl2, const void* __restrict__ bl2,
                    const void* __restrict__ bn7,
                    const void* __restrict__ Wl3, const void* __restrict__ bl3,
                    void* __restrict__ out){
  if (FLAG[0] != (BF ? 1 : 0)) return;
  __shared__ float hc[2048];
  __shared__ float h2s[512];
  __shared__ float h3s[256];
  int b = blockIdx.x, tid = threadIdx.x;
  for (int k = tid; k < 1024; k += 512){
    hc[k]        = key2f(hmaxk[b*1024 + k]);
    hc[1024 + k] = hsum[b*1024 + k] * (1.0f/2048.0f);
  }
  __syncthreads();
  {
    float acc = 0.f;
    for (int cc = 0; cc < 2048; cc += 8){
      float w[8];
      wload8<BF>(Wl1, (size_t)tid*2048 + cc, w);
      #pragma unroll
      for (int u = 0; u < 8; ++u) acc += w[u]*hc[cc+u];
    }
    float g = wget<BF>(bn6, tid), be = wget<BF>(bn6, 512+tid),
          mu = wget<BF>(bn6, 1024+tid), va = wget<BF>(bn6, 1536+tid);
    float sc = g / sqrtf(va + 1e-5f);
    h2s[tid] = lrelu((acc - mu)*sc + be);
  }
  __syncthreads();
  if (tid < 256){
    float acc = 0.f;
    for (int cc = 0; cc < 512; cc += 8){
      float w[8];
      wload8<BF>(Wl2, (size_t)tid*512 + cc, w);
      #pragma unroll
      for (int u = 0; u < 8; ++u) acc += w[u]*h2s[cc+u];
    }
    acc += wget<BF>(bl2, tid);
    float g = wget<BF>(bn7, tid), be = wget<BF>(bn7, 256+tid),
          mu = wget<BF>(bn7, 512+tid), va = wget<BF>(bn7, 768+tid);
    float sc = g / sqrtf(va + 1e-5f);
    h3s[tid] = lrelu((acc - mu)*sc + be);
  }
  __syncthreads();
  if (tid < 40){
    float acc = 0.f;
    for (int cc = 0; cc < 256; cc += 8){
      float w[8];
      wload8<BF>(Wl3, (size_t)tid*256 + cc, w);
      #pragma unroll
      for (int u = 0; u < 8; ++u) acc += w[u]*h3s[cc+u];
    }
    acc += wget<BF>(bl3, tid);
    if (BF) ((u16*)out)[b*40 + tid] = f2bu(acc);
    else    ((float*)out)[b*40 + tid] = acc;
  }
}

extern "C" void kernel_launch(void* const* d_in, const int* in_sizes, int n_in,
                              void* d_out, int out_size, void* d_ws, size_t ws_size,
                              hipStream_t stream){
  const void* x   = d_in[0];
  const void* W1  = d_in[1];
  const void* bn1 = d_in[2];
  const void* W2  = d_in[3];
  const void* bn2 = d_in[4];
  const void* W3  = d_in[5];
  const void* bn3 = d_in[6];
  const void* W4  = d_in[7];
  const void* bn4 = d_in[8];
  const void* W5  = d_in[9];
  const void* bn5 = d_in[10];
  const void* Wl1 = d_in[11];
  const void* bn6 = d_in[12];
  const void* Wl2 = d_in[13];
  const void* bl2 = d_in[14];
  const void* bn7 = d_in[15];
  const void* Wl3 = d_in[16];
  const void* bl3 = d_in[17];

  // ---- workspace layout (bytes), total 15,859,968 — fits the known-safe 16.33 MB ----
  char* base = (char*)d_ws;
  int*   FLAG  = (int*)  (base + 0);
  float* XT    = (float*)(base + 256);
  float* SQ    = (float*)(base + 393472);
  u32*   HMAXK = (u32*)  (base + 524544);
  float* HSUM  = (float*)(base + 590080);
  u16*   IDX1  = (u16*)  (base + 655616);
  u16*   IDX   = (u16*)  (base + 1966336);
  u16*   X2    = (u16*)  (base + 3277056);
  u16*   X3    = (u16*)  (base + 7471360);
  u16*   X1    = X3;                            // aliases X3: x1 dead before EC3 writes x3

  dim3 knnG1(NN/64, BB);
  dim3 knnGM(NN/32, BB);

  k_detect<<<1, 256, 0, stream>>>((const u16*)x, FLAG);

  k_prep<true ><<<PP/256, 256, 0, stream>>>(FLAG, x, XT, SQ, HMAXK, HSUM);
  k_prep<false><<<PP/256, 256, 0, stream>>>(FLAG, x, XT, SQ, HMAXK, HSUM);

  // EC1: XT (C=3) -> x1
  k_knn<3,128><<<knnG1, 256, 0, stream>>>(XT, SQ, IDX1);
  k_ec1<true ><<<PP/4, 256, 0, stream>>>(FLAG, XT, IDX1, W1, bn1, X1);
  k_ec1<false><<<PP/4, 256, 0, stream>>>(FLAG, XT, IDX1, W1, bn1, X1);

  // EC2: x1 -> x2 (MFMA edgeconv)
  k_sq<64><<<PP/256, 256, 0, stream>>>(X1, SQ);
  k_knn_mfma<64><<<knnGM, 256, 0, stream>>>(X1, SQ, IDX);
  k_ec<64,true ><<<PP/16, 256, 0, stream>>>(FLAG, X1, IDX, W2, bn2, X2);
  k_ec<64,false><<<PP/16, 256, 0, stream>>>(FLAG, X1, IDX, W2, bn2, X2);

  // EC3: x2 -> x3 (overwrites x1 region)
  k_sq<64><<<PP/256, 256, 0, stream>>>(X2, SQ);
  k_knn_mfma<64><<<knnGM, 256, 0, stream>>>(X2, SQ, IDX);
  k_ec<128,true ><<<PP/16, 256, 0, stream>>>(FLAG, X2, IDX, W3, bn3, X3);
  k_ec<128,false><<<PP/16, 256, 0, stream>>>(FLAG, X2, IDX, W3, bn3, X3);

  // EC4 KNN only (x4 recomputed inside k_w5f)
  k_sq<128><<<PP/256, 256, 0, stream>>>(X3, SQ);
  k_knn_mfma<128><<<knnGM, 256, 0, stream>>>(X3, SQ, IDX);

  // fused x1/x4 recompute + W5 + bn5 + act + global max/mean pooling (MFMA)
  k_w5f<true ><<<PP/PTS, 256, 0, stream>>>(FLAG, XT, IDX1, X2, X3, IDX,
                                           W1, bn1, W4, bn4, W5, bn5, HMAXK, HSUM);
  k_w5f<false><<<PP/PTS, 256, 0, stream>>>(FLAG, XT, IDX1, X2, X3, IDX,
                                           W1, bn1, W4, bn4, W5, bn5, HMAXK, HSUM);

  // head FCs
  k_head<true ><<<BB, 512, 0, stream>>>(FLAG, HMAXK, HSUM, Wl1, bn6, Wl2, bl2, bn7, Wl3, bl3, d_out);
  k_head<false><<<BB, 512, 0, stream>>>(FLAG, HMAXK, HSUM, Wl1, bn6, Wl2, bl2, bn7, Wl3, bl3, d_out);
}

// Round 9
// 2909.817 us; speedup vs baseline: 5.1999x; 1.8879x over previous
//
#include <hip/hip_runtime.h>
#include <hip/hip_bf16.h>

#define BB 16
#define NN 2048
#define PP (BB*NN)
#define KNN 20

typedef __hip_bfloat16 bf16;
typedef unsigned short u16;
typedef unsigned int u32;
typedef __attribute__((ext_vector_type(8))) short s8v;   // 8 bf16 = 4 VGPR (MFMA A/B frag)
typedef __attribute__((ext_vector_type(4))) float f4v;   // MFMA C/D frag

__device__ __forceinline__ float bu2f(u16 u){ return __uint_as_float(((u32)u) << 16); }
__device__ __forceinline__ float lo16(u32 u){ return __uint_as_float(u << 16); }
__device__ __forceinline__ float hi16(u32 u){ return __uint_as_float(u & 0xffff0000u); }
__device__ __forceinline__ u16 f2bu(float f){ bf16 h = __float2bfloat16(f); return *(u16*)&h; }
__device__ __forceinline__ float lrelu(float h){ return (h >= 0.f) ? h : 0.2f*h; }

__device__ __forceinline__ u32 f2key(float f){
  u32 u = __float_as_uint(f);
  return (u & 0x80000000u) ? ~u : (u | 0x80000000u);
}
__device__ __forceinline__ float key2f(u32 k){
  u32 u = (k & 0x80000000u) ? (k & 0x7FFFFFFFu) : ~k;
  return __uint_as_float(u);
}

template<bool BF> __device__ __forceinline__ float wget(const void* p, size_t i){
  return BF ? bu2f(((const u16*)p)[i]) : ((const float*)p)[i];
}
template<bool BF> __device__ __forceinline__ void wload8(const void* p, size_t base, float w[8]){
  if (BF){
    const uint4 u = *(const uint4*)((const u16*)p + base);
    w[0]=lo16(u.x); w[1]=hi16(u.x); w[2]=lo16(u.y); w[3]=hi16(u.y);
    w[4]=lo16(u.z); w[5]=hi16(u.z); w[6]=lo16(u.w); w[7]=hi16(u.w);
  } else {
    const float4* f = (const float4*)((const float*)p + base);
    float4 a = f[0], b = f[1];
    w[0]=a.x; w[1]=a.y; w[2]=a.z; w[3]=a.w; w[4]=b.x; w[5]=b.y; w[6]=b.z; w[7]=b.w;
  }
}

__device__ __forceinline__ f4v mfma16(s8v a, s8v b, f4v c){
  return __builtin_amdgcn_mfma_f32_16x16x32_bf16(a, b, c, 0, 0, 0);
}

// load 8 weights as hi/lo bf16 fragments (lo = residual; exact-weight MFMA via 2 ops)
template<bool BF> __device__ __forceinline__ void loadFragHL(const void* p, size_t base,
                                                             s8v& hi, s8v& lo){
  if (BF){
    hi = *(const s8v*)((const u16*)p + base);
  } else {
    float w[8]; wload8<false>(p, base, w);
    #pragma unroll
    for (int i = 0; i < 8; ++i){
      u16 hb = f2bu(w[i]);
      hi[i] = (short)hb;
      lo[i] = (short)f2bu(w[i] - bu2f(hb));
    }
  }
}
// hi/lo frags of (p[bb..] - p[ba..])
template<bool BF> __device__ __forceinline__ void loadDiffHL(const void* p, size_t ba, size_t bb,
                                                             s8v& hi, s8v& lo){
  float wa[8], wb[8];
  wload8<BF>(p, ba, wa); wload8<BF>(p, bb, wb);
  #pragma unroll
  for (int i = 0; i < 8; ++i){
    float d = wb[i] - wa[i];
    u16 hb = f2bu(d);
    hi[i] = (short)hb;
    lo[i] = (short)f2bu(d - bu2f(hb));
  }
}

// register-resident sorted (descending) top-20 insert; strict >, equal keeps earlier.
// Fully unrolled cndmask network — no LDS, no loop-carried branches.
__device__ __forceinline__ void topk_ins(float d, u32 id, float (&tv)[KNN], u32 (&ti)[KNN]){
  float pv = 0.f; u32 pi = 0u; bool cp = false;
  #pragma unroll
  for (int t = 0; t < KNN; ++t){
    bool c = (tv[t] < d);
    float ov = tv[t]; u32 oi = ti[t];
    tv[t] = c ? (cp ? pv : d) : tv[t];
    ti[t] = c ? (cp ? pi : id) : ti[t];
    pv = ov; pi = oi; cp = c;
  }
}

// ---------------- dtype detector: bf16 (1) vs fp32 (0) ------------------------------
__global__ void k_detect(const u16* __restrict__ xr, int* __restrict__ flag){
  __shared__ int cnt;
  if (threadIdx.x == 0) cnt = 0;
  __syncthreads();
  float v = bu2f(xr[threadIdx.x * 2]);
  float a = fabsf(v);
  int ok = (a > 1e-6f && a < 1e6f) ? 1 : 0;
  atomicAdd(&cnt, ok);
  __syncthreads();
  if (threadIdx.x == 0) flag[0] = (cnt >= 160) ? 1 : 0;
}

// ---------------- prep: transpose x [B,3,N] -> XT [P,3] fp32, SQ, pool init ---------
template<bool BF>
__global__ void k_prep(const int* __restrict__ FLAG, const void* __restrict__ x,
                       float* __restrict__ XT, float* __restrict__ SQ,
                       u32* __restrict__ hmaxk, float* __restrict__ hsum){
  if (FLAG[0] != (BF ? 1 : 0)) return;
  int i = blockIdx.x*256 + threadIdx.x;
  if (i >= PP) return;
  int b = i / NN, n = i - b*NN;
  float s = 0.f;
  #pragma unroll
  for (int c = 0; c < 3; ++c){
    float v = wget<BF>(x, ((size_t)b*3 + c)*NN + n);
    XT[(size_t)i*3 + c] = v;
    s += v*v;
  }
  SQ[i] = s;
  if (i < BB*1024){ hmaxk[i] = 0u; hsum[i] = 0.f; }
}

// ---------------- SQ[i] = sum_c x[i,c]^2 -------------------------------------------
template<int Cin>
__global__ void k_sq(const u16* __restrict__ xin, float* __restrict__ SQ){
  int i = blockIdx.x*256 + threadIdx.x;
  if (i >= PP) return;
  const u32* r = (const u32*)(xin + (size_t)i*Cin);
  float s = 0.f;
  for (int c = 0; c < Cin/2; ++c){
    u32 u = r[c];
    float a = lo16(u), b = hi16(u);
    s += a*a; s += b*b;
  }
  SQ[i] = s;
}

// ---------------- stage-1 KNN (C=3 fp32): block = 64 queries x 4 seg-waves ----------
// top-20 lists in REGISTERS during the scan; dumped to LDS once for the 4-way merge.
template<int C, int TC>
__global__ __launch_bounds__(256) void k_knn(const float* __restrict__ xin,
                                             const float* __restrict__ SQ,
                                             u16* __restrict__ IDX){
  __shared__ float cf[4][TC*C];
  __shared__ float csqv[4][TC];
  __shared__ float tvL[4][KNN][64];
  __shared__ u16   tiL[4][KNN][64];
  const int tid = threadIdx.x, w = tid >> 6, lane = tid & 63;
  const int b = blockIdx.y;
  const int q = blockIdx.x*64 + lane;
  const int j0 = w * 512;

  float qf[C];
  const float* xq = xin + ((size_t)b*NN + q)*C;
  #pragma unroll
  for (int c = 0; c < C; ++c) qf[c] = xq[c];
  const float sqq = SQ[b*NN + q];

  float tv[KNN]; u32 ti[KNN];
  #pragma unroll
  for (int t = 0; t < KNN; ++t){ tv[t] = -INFINITY; ti[t] = 0; }

  for (int t0 = 0; t0 < 512; t0 += TC){
    __syncthreads();
    const float* src = xin + ((size_t)b*NN + j0 + t0)*C;
    for (int k = lane; k < TC*C; k += 64) cf[w][k] = src[k];
    for (int k = lane; k < TC; k += 64) csqv[w][k] = SQ[b*NN + j0 + t0 + k];
    __syncthreads();
    for (int j = 0; j < TC; ++j){
      float dot = 0.f;
      #pragma unroll
      for (int c = 0; c < C; ++c) dot += qf[c]*cf[w][j*C + c];
      float d = 2.f*dot - sqq - csqv[w][j];
      if (d > tv[KNN-1]) topk_ins(d, (u32)(j0 + t0 + j), tv, ti);
    }
  }
  #pragma unroll
  for (int t = 0; t < KNN; ++t){ tvL[w][t][lane] = tv[t]; tiL[w][t][lane] = (u16)ti[t]; }
  __syncthreads();
  if (tid < 64){
    int p0=0,p1=0,p2=0,p3=0;
    u16* op = IDX + ((size_t)b*NN + q)*KNN;
    for (int t = 0; t < KNN; ++t){
      float v0 = tvL[0][p0][tid], v1 = tvL[1][p1][tid], v2 = tvL[2][p2][tid], v3 = tvL[3][p3][tid];
      int bs = 0; float bv = v0;
      if (v1 > bv){ bv = v1; bs = 1; }
      if (v2 > bv){ bv = v2; bs = 2; }
      if (v3 > bv){ bv = v3; bs = 3; }
      u16 bi;
      if      (bs == 0){ bi = tiL[0][p0][tid]; p0++; }
      else if (bs == 1){ bi = tiL[1][p1][tid]; p1++; }
      else if (bs == 2){ bi = tiL[2][p2][tid]; p2++; }
      else             { bi = tiL[3][p3][tid]; p3++; }
      op[t] = bi;
    }
  }
}

// ---------------- MFMA KNN (stages 2-4, bf16 features) ------------------------------
// Scores via 16x16x32 MFMA; top-20 lists in REGISTERS; LDS only for the final merge.
template<int C>
__global__ __launch_bounds__(256) void k_knn_mfma(const u16* __restrict__ xin,
                                                  const float* __restrict__ SQ,
                                                  u16* __restrict__ IDX){
  __shared__ float tvL[KNN][256];
  __shared__ u16   tiL[KNN][256];
  const int tid = threadIdx.x, w = tid >> 6, lane = tid & 63;
  const int quad = lane >> 4, n = lane & 15;
  const int seg = w & 1, qg = w >> 1;
  const int b = blockIdx.y;
  const int q = blockIdx.x*32 + qg*16 + n;
  const int cbase = seg * (NN/2);
  const u16* Xb = xin + (size_t)b*NN*C;

  s8v bfrag[C/32];
  #pragma unroll
  for (int kc = 0; kc < C/32; ++kc)
    bfrag[kc] = *(const s8v*)(Xb + (size_t)q*C + kc*32 + quad*8);
  const float sqq = SQ[b*NN + q];

  float tv[KNN]; u32 ti[KNN];
  #pragma unroll
  for (int t = 0; t < KNN; ++t){ tv[t] = -INFINITY; ti[t] = 0; }

  s8v afr[C/32], afn[C/32];
  #pragma unroll
  for (int kc = 0; kc < C/32; ++kc)
    afr[kc] = *(const s8v*)(Xb + (size_t)(cbase + n)*C + kc*32 + quad*8);

  for (int ct = cbase; ct < cbase + NN/2; ct += 16){
    int ctn = (ct + 16 < cbase + NN/2) ? (ct + 16) : cbase;
    #pragma unroll
    for (int kc = 0; kc < C/32; ++kc)
      afn[kc] = *(const s8v*)(Xb + (size_t)(ctn + n)*C + kc*32 + quad*8);
    f4v sqc = *(const f4v*)&SQ[b*NN + ct + quad*4];
    f4v acc = {0.f, 0.f, 0.f, 0.f};
    #pragma unroll
    for (int kc = 0; kc < C/32; ++kc)
      acc = mfma16(afr[kc], bfrag[kc], acc);
    #pragma unroll
    for (int r = 0; r < 4; ++r){
      float d = 2.f*acc[r] - sqq - sqc[r];
      if (d > tv[KNN-1]) topk_ins(d, (u32)(ct + quad*4 + r), tv, ti);
    }
    #pragma unroll
    for (int kc = 0; kc < C/32; ++kc) afr[kc] = afn[kc];
  }
  #pragma unroll
  for (int t = 0; t < KNN; ++t){ tvL[t][tid] = tv[t]; tiL[t][tid] = (u16)ti[t]; }
  __syncthreads();

  if (tid < 32){
    int mn = tid & 15, mqg = tid >> 4;
    int mq = blockIdx.x*32 + mqg*16 + mn;
    int p[8] = {0,0,0,0,0,0,0,0};
    u16* op = IDX + ((size_t)b*NN + mq)*KNN;
    for (int t = 0; t < KNN; ++t){
      float bv = -INFINITY; int bs = 0; u16 bi = 0xFFFF;
      #pragma unroll
      for (int s = 0; s < 8; ++s){
        int col = mqg*128 + (s >> 2)*64 + (s & 3)*16 + mn;
        float v = tvL[p[s]][col];
        u16  ii = tiL[p[s]][col];
        if (v > bv || (v == bv && ii < bi)){ bv = v; bs = s; bi = ii; }
      }
      op[t] = bi; p[bs]++;
    }
  }
}

// ---------------- EC1 direct (C=3 -> O=64): block = 4 points x 64 channels ----------
template<bool BF>
__global__ __launch_bounds__(256) void k_ec1(const int* __restrict__ FLAG,
                    const float* __restrict__ XT,
                    const u16* __restrict__ IDX1, const void* __restrict__ W1,
                    const void* __restrict__ bn1, u16* __restrict__ x1out){
  if (FLAG[0] != (BF ? 1 : 0)) return;
  __shared__ float nbx[4][21][3];
  __shared__ float W1s[384];
  __shared__ float bn1s[256];
  __shared__ u16   idxL[4][KNN];
  const int tid = threadIdx.x;
  const int g0 = blockIdx.x*4, b = g0 / NN;
  for (int k = tid; k < 384; k += 256) W1s[k] = wget<BF>(W1, k);
  if (tid < 256) bn1s[tid] = wget<BF>(bn1, tid);
  if (tid < 80){ int pt = tid/KNN, t = tid%KNN; idxL[pt][t] = IDX1[(size_t)(g0+pt)*KNN + t]; }
  __syncthreads();
  for (int k = tid; k < 4*21*3; k += 256){
    int row = k/3, c = k - row*3;
    int pt = row/21, slot = row - pt*21;
    int m = (slot < KNN) ? (int)idxL[pt][slot] : (g0 + pt - b*NN);
    nbx[pt][slot][c] = XT[((size_t)b*NN + m)*3 + c];
  }
  __syncthreads();
  int pt = tid >> 6, o = tid & 63;
  float wa0 = W1s[o*6], wa1 = W1s[o*6+1], wa2 = W1s[o*6+2];
  float wb0 = W1s[o*6+3], wb1 = W1s[o*6+4], wb2 = W1s[o*6+5];
  float pmax = -INFINITY;
  #pragma unroll
  for (int t = 0; t < KNN; ++t)
    pmax = fmaxf(pmax, nbx[pt][t][0]*wa0 + nbx[pt][t][1]*wa1 + nbx[pt][t][2]*wa2);
  float po = nbx[pt][20][0]*wa0 + nbx[pt][20][1]*wa1 + nbx[pt][20][2]*wa2;
  float qo = nbx[pt][20][0]*wb0 + nbx[pt][20][1]*wb1 + nbx[pt][20][2]*wb2;
  float h = pmax - po + qo;
  float sc = bn1s[o] / sqrtf(bn1s[192+o] + 1e-5f);
  h = (h - bn1s[128+o])*sc + bn1s[64+o];
  x1out[(size_t)(g0+pt)*64 + o] = f2bu(lrelu(h));
}

// ---------------- MFMA edgeconv (EC2/EC3): block = 16 points, 4 waves ---------------
template<int O_, bool BF>
__global__ __launch_bounds__(256, 2) void k_ec(const int* __restrict__ FLAG,
                    const u16* __restrict__ xin, const u16* __restrict__ idx,
                    const void* __restrict__ W, const void* __restrict__ bn,
                    u16* __restrict__ xout){
  if (FLAG[0] != (BF ? 1 : 0)) return;
  __shared__ __align__(16) u16 ANu[16*24*72];    // 55.3 KB
  __shared__ u16 idxL[16][KNN];
  const int tid = threadIdx.x, wv = tid >> 6, lane = tid & 63;
  const int quad = lane >> 4, n = lane & 15;
  const int g0 = blockIdx.x*16, b = g0 / NN, n0 = g0 - b*NN;

  for (int k = tid; k < 16*KNN; k += 256){
    int pt = k/KNN, t = k - pt*KNN;
    idxL[pt][t] = idx[(size_t)(g0+pt)*KNN + t];
  }
  __syncthreads();
  u32* ANw = (u32*)ANu;
  for (int k = tid; k < 384*32; k += 256){
    int row = k >> 5, pr = k & 31;
    int pt = row/24, r = row - pt*24;
    int m = (r < KNN) ? (int)idxL[pt][r] : (n0 + pt);
    ANw[row*36 + pr] = ((const u32*)(xin + ((size_t)b*NN + m)*64))[pr];
  }
  __syncthreads();

  s8v aself[2];
  #pragma unroll
  for (int kc = 0; kc < 2; ++kc)
    aself[kc] = *(const s8v*)&ANu[((lane&15)*24 + 20)*72 + kc*32 + quad*8];

  for (int tt = wv; tt < O_/16; tt += 4){
    const int o = tt*16 + n;
    s8v bah[2], bal[2], bdh[2], bdl[2];
    #pragma unroll
    for (int kc = 0; kc < 2; ++kc){
      loadFragHL<BF>(W, (size_t)o*128 + kc*32 + quad*8, bah[kc], bal[kc]);
      loadDiffHL<BF>(W, (size_t)o*128 + kc*32 + quad*8,
                        (size_t)o*128 + 64 + kc*32 + quad*8, bdh[kc], bdl[kc]);
    }
    f4v accq = {0.f,0.f,0.f,0.f};
    #pragma unroll
    for (int kc = 0; kc < 2; ++kc){
      accq = mfma16(aself[kc], bdh[kc], accq);
      accq = mfma16(aself[kc], bdl[kc], accq);
    }
    float g  = wget<BF>(bn, o),        be = wget<BF>(bn, O_+o),
          mu = wget<BF>(bn, 2*O_+o),   va = wget<BF>(bn, 3*O_+o);
    float sc = g / sqrtf(va + 1e-5f);

    #pragma unroll
    for (int pt = 0; pt < 16; ++pt){
      s8v a0[2], a1[2];
      #pragma unroll
      for (int kc = 0; kc < 2; ++kc){
        a0[kc] = *(const s8v*)&ANu[(pt*24 + (lane&15))*72 + kc*32 + quad*8];
        a1[kc] = *(const s8v*)&ANu[(pt*24 + 16 + (lane&7))*72 + kc*32 + quad*8];
      }
      f4v c0 = {0.f,0.f,0.f,0.f}, c1 = {0.f,0.f,0.f,0.f};
      #pragma unroll
      for (int kc = 0; kc < 2; ++kc){
        c0 = mfma16(a0[kc], bah[kc], c0);
        c1 = mfma16(a1[kc], bah[kc], c1);
        if (!BF){
          c0 = mfma16(a0[kc], bal[kc], c0);
          c1 = mfma16(a1[kc], bal[kc], c1);
        }
      }
      float pm = fmaxf(fmaxf(fmaxf(c0[0],c0[1]), fmaxf(c0[2],c0[3])),
                       fmaxf(fmaxf(c1[0],c1[1]), fmaxf(c1[2],c1[3])));
      pm = fmaxf(pm, __shfl_xor(pm, 16));
      pm = fmaxf(pm, __shfl_xor(pm, 32));
      if (quad == (pt >> 2)){
        float h = pm + accq[pt & 3];
        h = (h - mu)*sc + be;
        xout[(size_t)(g0+pt)*O_ + o] = f2bu(lrelu(h));
      }
    }
  }
}

// ---------------- fused MFMA: x1 + x4 recompute + W5 + BN5 + act + pooling ----------
// PTS=16, 512 threads (8 waves), 1 block/CU: halves per-point weight streaming.
#define PTS 16
template<bool BF>
__global__ __launch_bounds__(512, 1) void k_w5f(const int* __restrict__ FLAG,
      const float* __restrict__ XT,
      const u16* __restrict__ IDX1, const u16* __restrict__ x2g, const u16* __restrict__ x3g,
      const u16* __restrict__ IDX4,
      const void* __restrict__ W1, const void* __restrict__ bn1,
      const void* __restrict__ W4, const void* __restrict__ bn4,
      const void* __restrict__ W5, const void* __restrict__ bn5,
      u32* __restrict__ hmaxk, float* __restrict__ hsum){
  if (FLAG[0] != (BF ? 1 : 0)) return;
  __shared__ __align__(16) u16 ANu[PTS*24*136];   // 104.4 KB
  __shared__ __align__(16) u16 xsu[PTS*520];      // 16.6 KB
  __shared__ float xtn[PTS][21][3];
  __shared__ u16   idx1L[PTS][KNN], idx4L[PTS][KNN];
  __shared__ float W1s[384], bn1s[256], bn4s[1024];
  const int tid = threadIdx.x, wv = tid >> 6, lane = tid & 63;
  const int quad = lane >> 4, n = lane & 15;
  const int g0 = blockIdx.x*PTS, b = g0 / NN, n0 = g0 - b*NN;

  for (int k = tid; k < PTS*KNN; k += 512){
    int pt = k/KNN, t = k - pt*KNN;
    idx1L[pt][t] = IDX1[(size_t)(g0+pt)*KNN + t];
    idx4L[pt][t] = IDX4[(size_t)(g0+pt)*KNN + t];
  }
  if (tid < 384) W1s[tid] = wget<BF>(W1, tid);
  if (tid < 256) bn1s[tid] = wget<BF>(bn1, tid);
  for (int k = tid; k < 1024; k += 512) bn4s[k] = wget<BF>(bn4, k);
  __syncthreads();

  u32* ANw = (u32*)ANu;
  for (int k = tid; k < PTS*24*64; k += 512){
    int row = k >> 6, pr = k & 63;
    int pt = row/24, r = row - pt*24;
    int m = (r < KNN) ? (int)idx4L[pt][r] : (n0 + pt);
    ANw[(pt*24 + r)*68 + pr] = ((const u32*)(x3g + ((size_t)b*NN + m)*128))[pr];
  }
  for (int k = tid; k < PTS*21*3; k += 512){
    int row = k/3, c = k - row*3;
    int pt = row/21, slot = row - pt*21;
    int m = (slot < KNN) ? (int)idx1L[pt][slot] : (n0 + pt);
    xtn[pt][slot][c] = XT[((size_t)b*NN + m)*3 + c];
  }
  u32* xsw = (u32*)xsu;
  for (int k = tid; k < PTS*32; k += 512){
    int pt = k >> 5, c2 = k & 31;
    xsw[pt*260 + 32 + c2] = ((const u32*)(x2g + (size_t)(g0+pt)*64))[c2];
  }
  for (int k = tid; k < PTS*64; k += 512){
    int pt = k >> 6, c2 = k & 63;
    xsw[pt*260 + 64 + c2] = ((const u32*)(x3g + (size_t)(g0+pt)*128))[c2];
  }
  __syncthreads();

  // x1 recompute -> xsu cols 0..63
  #pragma unroll
  for (int hh = 0; hh < PTS*64/512; ++hh){
    int k = tid + hh*512;
    int pt = k >> 6, o = k & 63;
    float wa0 = W1s[o*6], wa1 = W1s[o*6+1], wa2 = W1s[o*6+2];
    float wb0 = W1s[o*6+3], wb1 = W1s[o*6+4], wb2 = W1s[o*6+5];
    float pmax = -INFINITY;
    #pragma unroll
    for (int t = 0; t < KNN; ++t)
      pmax = fmaxf(pmax, xtn[pt][t][0]*wa0 + xtn[pt][t][1]*wa1 + xtn[pt][t][2]*wa2);
    float po = xtn[pt][20][0]*wa0 + xtn[pt][20][1]*wa1 + xtn[pt][20][2]*wa2;
    float qo = xtn[pt][20][0]*wb0 + xtn[pt][20][1]*wb1 + xtn[pt][20][2]*wb2;
    float h = pmax - po + qo;
    float sc = bn1s[o] / sqrtf(bn1s[192+o] + 1e-5f);
    h = (h - bn1s[128+o])*sc + bn1s[64+o];
    xsu[pt*520 + o] = f2bu(lrelu(h));
  }

  // ---- x4 via MFMA: 16 out-tiles over 8 waves (2 each) ----
  {
    s8v aself[4];
    #pragma unroll
    for (int kc = 0; kc < 4; ++kc)
      aself[kc] = *(const s8v*)&ANu[((lane&15)*24 + 20)*136 + kc*32 + quad*8];

    for (int i = 0; i < 2; ++i){
      const int o0 = (wv*2 + i)*16;
      const size_t wrow = (size_t)(o0 + n)*256;
      s8v bah[4], bal[4], bdh[4], bdl[4];
      #pragma unroll
      for (int kc = 0; kc < 4; ++kc){
        loadFragHL<BF>(W4, wrow + kc*32 + quad*8, bah[kc], bal[kc]);
        loadDiffHL<BF>(W4, wrow + kc*32 + quad*8, wrow + 128 + kc*32 + quad*8, bdh[kc], bdl[kc]);
      }
      f4v accq = {0.f,0.f,0.f,0.f};
      #pragma unroll
      for (int kc = 0; kc < 4; ++kc){
        accq = mfma16(aself[kc], bdh[kc], accq);
        accq = mfma16(aself[kc], bdl[kc], accq);
      }
      #pragma unroll
      for (int pt = 0; pt < PTS; ++pt){
        s8v a0[4], a1[4];
        #pragma unroll
        for (int kc = 0; kc < 4; ++kc){
          a0[kc] = *(const s8v*)&ANu[(pt*24 + (lane&15))*136 + kc*32 + quad*8];
          a1[kc] = *(const s8v*)&ANu[(pt*24 + 16 + (lane&7))*136 + kc*32 + quad*8];
        }
        f4v c0 = {0.f,0.f,0.f,0.f}, c1 = {0.f,0.f,0.f,0.f};
        #pragma unroll
        for (int kc = 0; kc < 4; ++kc){
          c0 = mfma16(a0[kc], bah[kc], c0);
          c1 = mfma16(a1[kc], bah[kc], c1);
          if (!BF){
            c0 = mfma16(a0[kc], bal[kc], c0);
            c1 = mfma16(a1[kc], bal[kc], c1);
          }
        }
        float pm = fmaxf(fmaxf(fmaxf(c0[0],c0[1]), fmaxf(c0[2],c0[3])),
                         fmaxf(fmaxf(c1[0],c1[1]), fmaxf(c1[2],c1[3])));
        pm = fmaxf(pm, __shfl_xor(pm, 16));
        pm = fmaxf(pm, __shfl_xor(pm, 32));
        if (quad == (pt >> 2)){
          float h = pm + accq[pt & 3];
          int o = o0 + n;
          float sc = bn4s[o] / sqrtf(bn4s[768+o] + 1e-5f);
          h = (h - bn4s[512+o])*sc + bn4s[256+o];
          xsu[pt*520 + 256 + o] = f2bu(lrelu(h));
        }
      }
    }
  }
  __syncthreads();

  // ---- W5 via MFMA: 64 out-tiles over 8 waves (8 each); A rows = 16 points ----
  {
    s8v afr[16];
    #pragma unroll
    for (int kc = 0; kc < 16; ++kc)
      afr[kc] = *(const s8v*)&xsu[(lane&15)*520 + kc*32 + quad*8];

    for (int i = 0; i < 8; ++i){
      const int o = (wv*8 + i)*16 + n;
      const size_t wrow = (size_t)o * 512;
      f4v acc = {0.f,0.f,0.f,0.f};
      #pragma unroll
      for (int kc = 0; kc < 16; ++kc){
        s8v bh, bl;
        loadFragHL<BF>(W5, wrow + kc*32 + quad*8, bh, bl);
        acc = mfma16(afr[kc], bh, acc);
        if (!BF) acc = mfma16(afr[kc], bl, acc);
      }
      float g = wget<BF>(bn5, o), be = wget<BF>(bn5, 1024+o),
            mu = wget<BF>(bn5, 2048+o), va = wget<BF>(bn5, 3072+o);
      float sc = g / sqrtf(va + 1e-5f);
      float lm = -INFINITY, ls = 0.f;
      #pragma unroll
      for (int r = 0; r < 4; ++r){
        float h = (acc[r] - mu)*sc + be;
        h = lrelu(h);
        lm = fmaxf(lm, h); ls += h;
      }
      lm = fmaxf(lm, __shfl_xor(lm, 16));
      ls = ls + __shfl_xor(ls, 16);
      lm = fmaxf(lm, __shfl_xor(lm, 32));
      ls = ls + __shfl_xor(ls, 32);
      if (quad == 0){
        atomicMax(&hmaxk[b*1024 + o], f2key(lm));
        atomicAdd(&hsum[b*1024 + o], ls);
      }
    }
  }
}

// ---------------- head: [max|mean] -> FC512 -> FC256 -> FC40 ------------------------
template<bool BF>
__global__ __launch_bounds__(512) void k_head(const int* __restrict__ FLAG,
                    const u32* __restrict__ hmaxk, const float* __restrict__ hsum,
                    const void* __restrict__ Wl1, const void* __restrict__ bn6,
                    const void* __restrict__ Wl2, const void* __restrict__ bl2,
                    const void* __restrict__ bn7,
                    const void* __restrict__ Wl3, const void* __restrict__ bl3,
                    void* __restrict__ out){
  if (FLAG[0] != (BF ? 1 : 0)) return;
  __shared__ float hc[2048];
  __shared__ float h2s[512];
  __shared__ float h3s[256];
  int b = blockIdx.x, tid = threadIdx.x;
  for (int k = tid; k < 1024; k += 512){
    hc[k]        = key2f(hmaxk[b*1024 + k]);
    hc[1024 + k] = hsum[b*1024 + k] * (1.0f/2048.0f);
  }
  __syncthreads();
  {
    float acc = 0.f;
    for (int cc = 0; cc < 2048; cc += 8){
      float w[8];
      wload8<BF>(Wl1, (size_t)tid*2048 + cc, w);
      #pragma unroll
      for (int u = 0; u < 8; ++u) acc += w[u]*hc[cc+u];
    }
    float g = wget<BF>(bn6, tid), be = wget<BF>(bn6, 512+tid),
          mu = wget<BF>(bn6, 1024+tid), va = wget<BF>(bn6, 1536+tid);
    float sc = g / sqrtf(va + 1e-5f);
    h2s[tid] = lrelu((acc - mu)*sc + be);
  }
  __syncthreads();
  if (tid < 256){
    float acc = 0.f;
    for (int cc = 0; cc < 512; cc += 8){
      float w[8];
      wload8<BF>(Wl2, (size_t)tid*512 + cc, w);
      #pragma unroll
      for (int u = 0; u < 8; ++u) acc += w[u]*h2s[cc+u];
    }
    acc += wget<BF>(bl2, tid);
    float g = wget<BF>(bn7, tid), be = wget<BF>(bn7, 256+tid),
          mu = wget<BF>(bn7, 512+tid), va = wget<BF>(bn7, 768+tid);
    float sc = g / sqrtf(va + 1e-5f);
    h3s[tid] = lrelu((acc - mu)*sc + be);
  }
  __syncthreads();
  if (tid < 40){
    float acc = 0.f;
    for (int cc = 0; cc < 256; cc += 8){
      float w[8];
      wload8<BF>(Wl3, (size_t)tid*256 + cc, w);
      #pragma unroll
      for (int u = 0; u < 8; ++u) acc += w[u]*h3s[cc+u];
    }
    acc += wget<BF>(bl3, tid);
    if (BF) ((u16*)out)[b*40 + tid] = f2bu(acc);
    else    ((float*)out)[b*40 + tid] = acc;
  }
}

extern "C" void kernel_launch(void* const* d_in, const int* in_sizes, int n_in,
                              void* d_out, int out_size, void* d_ws, size_t ws_size,
                              hipStream_t stream){
  const void* x   = d_in[0];
  const void* W1  = d_in[1];
  const void* bn1 = d_in[2];
  const void* W2  = d_in[3];
  const void* bn2 = d_in[4];
  const void* W3  = d_in[5];
  const void* bn3 = d_in[6];
  const void* W4  = d_in[7];
  const void* bn4 = d_in[8];
  const void* W5  = d_in[9];
  const void* bn5 = d_in[10];
  const void* Wl1 = d_in[11];
  const void* bn6 = d_in[12];
  const void* Wl2 = d_in[13];
  const void* bl2 = d_in[14];
  const void* bn7 = d_in[15];
  const void* Wl3 = d_in[16];
  const void* bl3 = d_in[17];

  // ---- workspace layout (bytes), total 15,859,968 — fits the known-safe 16.33 MB ----
  char* base = (char*)d_ws;
  int*   FLAG  = (int*)  (base + 0);
  float* XT    = (float*)(base + 256);
  float* SQ    = (float*)(base + 393472);
  u32*   HMAXK = (u32*)  (base + 524544);
  float* HSUM  = (float*)(base + 590080);
  u16*   IDX1  = (u16*)  (base + 655616);
  u16*   IDX   = (u16*)  (base + 1966336);
  u16*   X2    = (u16*)  (base + 3277056);
  u16*   X3    = (u16*)  (base + 7471360);
  u16*   X1    = X3;                            // aliases X3: x1 dead before EC3 writes x3

  dim3 knnG1(NN/64, BB);
  dim3 knnGM(NN/32, BB);

  k_detect<<<1, 256, 0, stream>>>((const u16*)x, FLAG);

  k_prep<true ><<<PP/256, 256, 0, stream>>>(FLAG, x, XT, SQ, HMAXK, HSUM);
  k_prep<false><<<PP/256, 256, 0, stream>>>(FLAG, x, XT, SQ, HMAXK, HSUM);

  // EC1: XT (C=3) -> x1
  k_knn<3,128><<<knnG1, 256, 0, stream>>>(XT, SQ, IDX1);
  k_ec1<true ><<<PP/4, 256, 0, stream>>>(FLAG, XT, IDX1, W1, bn1, X1);
  k_ec1<false><<<PP/4, 256, 0, stream>>>(FLAG, XT, IDX1, W1, bn1, X1);

  // EC2: x1 -> x2 (MFMA edgeconv)
  k_sq<64><<<PP/256, 256, 0, stream>>>(X1, SQ);
  k_knn_mfma<64><<<knnGM, 256, 0, stream>>>(X1, SQ, IDX);
  k_ec<64,true ><<<PP/16, 256, 0, stream>>>(FLAG, X1, IDX, W2, bn2, X2);
  k_ec<64,false><<<PP/16, 256, 0, stream>>>(FLAG, X1, IDX, W2, bn2, X2);

  // EC3: x2 -> x3 (overwrites x1 region)
  k_sq<64><<<PP/256, 256, 0, stream>>>(X2, SQ);
  k_knn_mfma<64><<<knnGM, 256, 0, stream>>>(X2, SQ, IDX);
  k_ec<128,true ><<<PP/16, 256, 0, stream>>>(FLAG, X2, IDX, W3, bn3, X3);
  k_ec<128,false><<<PP/16, 256, 0, stream>>>(FLAG, X2, IDX, W3, bn3, X3);

  // EC4 KNN only (x4 recomputed inside k_w5f)
  k_sq<128><<<PP/256, 256, 0, stream>>>(X3, SQ);
  k_knn_mfma<128><<<knnGM, 256, 0, stream>>>(X3, SQ, IDX);

  // fused x1/x4 recompute + W5 + bn5 + act + global max/mean pooling (MFMA, PTS=16)
  k_w5f<true ><<<PP/PTS, 512, 0, stream>>>(FLAG, XT, IDX1, X2, X3, IDX,
                                           W1, bn1, W4, bn4, W5, bn5, HMAXK, HSUM);
  k_w5f<false><<<PP/PTS, 512, 0, stream>>>(FLAG, XT, IDX1, X2, X3, IDX,
                                           W1, bn1, W4, bn4, W5, bn5, HMAXK, HSUM);

  // head FCs
  k_head<true ><<<BB, 512, 0, stream>>>(FLAG, HMAXK, HSUM, Wl1, bn6, Wl2, bl2, bn7, Wl3, bl3, d_out);
  k_head<false><<<BB, 512, 0, stream>>>(FLAG, HMAXK, HSUM, Wl1, bn6, Wl2, bl2, bn7, Wl3, bl3, d_out);
}